// Round 11
// baseline (30415.567 us; speedup 1.0000x reference)
//
#include <hip/hip_runtime.h>
#include <math.h>

// ---------------- problem sizes ----------------
#define NN   2048   // source length
#define TLEN 2048   // target length
#define TTAG 64     // tags
#define VOC  50257
#define GW   32     // decoder blocks; each owns CHK source rows + 3-4 hidden units
#define CHK  64     // source rows per block
#define RECU 80     // u64 stride per record (68 used)
static_assert(GW * CHK == NN, "chunking");

// ---------------- workspace layout (float units) ----------------
#define OFF_XF    0                          // NN*400
#define OFF_XB    (OFF_XF  + NN*400)         // NN*400
#define OFF_TGX   (OFF_XB  + NN*400)         // TTAG*400
#define OFF_PEW   (OFF_TGX + TTAG*400)       // TLEN*400
#define OFF_ENC   (OFF_PEW + TLEN*400)       // NN*200
#define OFF_W1DT  (OFF_ENC + NN*200)         // NN*100
#define OFF_TAGV  (OFF_W1DT+ NN*100)         // TTAG*100
#define OFF_TGW1  (OFF_TAGV+ TTAG*100)       // TTAG*100
#define OFF_TGW   (OFF_TGW1+ TTAG*100)       // TTAG*400
#define OFF_HOUT  (OFF_TGW + TTAG*400)       // TLEN*100
#define OFF_REC   (OFF_HOUT+ TLEN*100)       // 2*GW*RECU u64
#define OFF_HC    (OFF_REC + 2*GW*RECU*2)    // 2*128 u64 (seq-embedded h/c words)
#define OFF_FLG   (OFF_HC  + 2*128*2)        // 2048 u64 flags (128B-spread; record flags)
#define OFF_PB    (OFF_FLG + 4096)           // loss partials

// record u64 words: [0..49] ctxp 4xbf16/word, [50..65] scores 4xbf16/word (64 rows),
//   [66]={m f32 | S f32}, [67]={amax f32 | idx}   (flag+bulk protocol)
// hc buffer b: word u = { h bf16 | c bf16 | seq u32 }  (single-trip, seq-embedded)
// Unit owners keep their own h,c in f32 registers for the gates; bf16 copies
// are only consumed by attention (whose other inputs are already bf16).

// ---------------- helpers ----------------
__device__ __forceinline__ float rcpf(float x){ return __builtin_amdgcn_rcpf(x); }
__device__ __forceinline__ float sigf(float x){ return rcpf(1.0f+__expf(-x)); }
__device__ __forceinline__ float tanhfast(float x){
  float e = __expf(2.0f*x);
  return 1.0f - 2.0f*rcpf(e+1.0f);
}
__device__ __forceinline__ unsigned short f2b(float x){
  unsigned b=__float_as_uint(x);
  return (unsigned short)((b + 0x7fffu + ((b>>16)&1u))>>16);
}
__device__ __forceinline__ unsigned pk2(float a,float b){ return (unsigned)f2b(a) | ((unsigned)f2b(b)<<16); }
__device__ __forceinline__ float blo(unsigned u){ return __uint_as_float(u<<16); }
__device__ __forceinline__ float bhi(unsigned u){ return __uint_as_float(u&0xffff0000u); }

__device__ __forceinline__ unsigned long long ald64(const unsigned long long* p){
  return __hip_atomic_load(p,__ATOMIC_RELAXED,__HIP_MEMORY_SCOPE_SYSTEM);
}
__device__ __forceinline__ void ast64(unsigned long long* p, unsigned long long v){
  __hip_atomic_store(p,v,__ATOMIC_RELAXED,__HIP_MEMORY_SCOPE_SYSTEM);
}
__device__ __forceinline__ void vm0(){ asm volatile("s_waitcnt vmcnt(0)" ::: "memory"); }

// ---------------- kInit: zero flag region (every launch / replay) ----------------
__global__ void kInit(float* ws){
  unsigned long long* f = (unsigned long long*)(ws + OFF_FLG);
  int i = blockIdx.x*256 + threadIdx.x;
  if (i < 2048) ast64(f+i, 0ull);
}

// ---------------- kPrep: all input-side GEMVs (parallel) ----------------
__global__ __launch_bounds__(512) void kPrep(
    const int* src, const int* tag, const int* oid,
    const float* emb_char, const float* emb_tag,
    const float* fWih, const float* fb,
    const float* bWih, const float* bb,
    const float* tWih, const float* tb,
    const float* dWih, const float* db, float* ws)
{
  int r = blockIdx.x, j = threadIdx.x;
  if (j >= 400) return;
  if (r < NN) {
    const float* e = emb_char + (size_t)src[r]*32;
    const float* Wr = fWih + j*32;
    float a = fb[j];
    #pragma unroll
    for (int q=0;q<32;q++) a += e[q]*Wr[q];
    ws[OFF_XF + r*400 + j] = a;
  } else if (r < 2*NN) {
    int n = r - NN;
    const float* e = emb_char + (size_t)src[n]*32;
    const float* Wr = bWih + j*32;
    float a = bb[j];
    #pragma unroll
    for (int q=0;q<32;q++) a += e[q]*Wr[q];
    ws[OFF_XB + n*400 + j] = a;
  } else if (r < 2*NN + TTAG) {
    int s = r - 2*NN;
    const float* e = emb_tag + (size_t)tag[s]*32;
    const float* Wr = tWih + j*32;
    float a = tb[j];
    #pragma unroll
    for (int q=0;q<32;q++) a += e[q]*Wr[q];
    ws[OFF_TGX + s*400 + j] = a;
  } else {
    int t = r - (2*NN + TTAG);
    int pid = (t==0) ? 0 : oid[t-1];
    const float* e = emb_char + (size_t)pid*32;
    const float* Wr = dWih + (size_t)j*332 + 300;
    float a = db[j];
    #pragma unroll
    for (int q=0;q<32;q++) a += e[q]*Wr[q];
    ws[OFF_PEW + t*400 + j] = a;
  }
}

// ---------------- kEnc: sequential LSTM scans (3 independent blocks) ----------------
// z-loops FULLY unrolled so whh[100] stays in VGPRs (runtime-indexed register
// arrays spill to scratch — that was 10 ms of the R9 profile).
struct EncShared {
  float tvs[TTAG*100];
  float sa [TTAG*64];
  float hbuf[100];
  float zbuf[400];
};

__device__ void lstm_block(const float* Whh, const float* xbase, float* ws,
                           int reverse, int col, EncShared* sh)
{
  int tid = threadIdx.x;
  float whh[100];
  if (tid < 400){
    #pragma unroll
    for (int k=0;k<100;k++) whh[k] = Whh[tid*100+k];
  }
  float c = 0.f;
  if (tid < 100) sh->hbuf[tid] = 0.f;
  __syncthreads();
  for (int i=0;i<NN;i++){
    int n = reverse ? (NN-1-i) : i;
    if (tid < 400){
      float z = xbase[n*400+tid];
      #pragma unroll
      for (int k=0;k<100;k++) z += whh[k]*sh->hbuf[k];
      sh->zbuf[tid] = z;
    }
    __syncthreads();
    if (tid < 100){
      float zi=sh->zbuf[tid], zf=sh->zbuf[tid+100], zg=sh->zbuf[tid+200], zo=sh->zbuf[tid+300];
      c = sigf(zf)*c + sigf(zi)*tanhfast(zg);
      float h = sigf(zo)*tanhfast(c);
      sh->hbuf[tid] = h;
      ws[OFF_ENC + n*200 + col + tid] = h;
    }
    __syncthreads();
  }
}

__global__ __launch_bounds__(512,1) void kEnc(
    const float* fWhh, const float* bWhh, const float* tWhh,
    const float* taw1, const float* dWih, float* ws)
{
  __shared__ EncShared sh;
  int b = blockIdx.x, tid = threadIdx.x;
  if (b == 0){ lstm_block(fWhh, ws+OFF_XF, ws, 0, 0,   &sh); return; }
  if (b == 1){ lstm_block(bWhh, ws+OFF_XB, ws, 1, 100, &sh); return; }

  // ---- block 2: tag LSTM + self-attn + tagv-derived tables ----
  {
    float whh[100];
    if (tid<400){
      #pragma unroll
      for (int k=0;k<100;k++) whh[k] = tWhh[tid*100+k];
    }
    float c = 0.f;
    if (tid<100) sh.hbuf[tid] = 0.f;
    __syncthreads();
    for (int s=0;s<TTAG;s++){
      if (tid<400){
        float z = ws[OFF_TGX + s*400 + tid];
        #pragma unroll
        for (int k=0;k<100;k++) z += whh[k]*sh.hbuf[k];
        sh.zbuf[tid] = z;
      }
      __syncthreads();
      if (tid<100){
        float zi=sh.zbuf[tid], zf=sh.zbuf[tid+100], zg=sh.zbuf[tid+200], zo=sh.zbuf[tid+300];
        c = sigf(zf)*c + sigf(zi)*tanhfast(zg);
        float h = sigf(zo)*tanhfast(c);
        sh.hbuf[tid] = h;
        sh.tvs[s*100+tid] = h;
      }
      __syncthreads();
    }
  }
  for (int idx=tid; idx<TTAG*TTAG; idx+=512){
    int s=idx>>6, t2=idx&63;
    float a=0.f;
    #pragma unroll 10
    for (int h=0;h<100;h++) a += sh.tvs[s*100+h]*sh.tvs[t2*100+h];
    sh.sa[idx]=a;
  }
  __syncthreads();
  if (tid<TTAG){
    float m=-1e30f;
    for (int t2=0;t2<64;t2++) m = fmaxf(m, sh.sa[tid*64+t2]);
    float sum=0.f;
    for (int t2=0;t2<64;t2++){ float e=__expf(sh.sa[tid*64+t2]-m); sh.sa[tid*64+t2]=e; sum+=e; }
    float r=1.f/sum;
    for (int t2=0;t2<64;t2++) sh.sa[tid*64+t2]*=r;
  }
  __syncthreads();
  float tvloc[13]; int cnt=0;
  for (int idx=tid; idx<TTAG*100; idx+=512){
    int t2=idx/100, hh=idx%100;
    float a = sh.tvs[t2*100+hh];
    for (int s=0;s<64;s++) a += sh.tvs[s*100+hh]*sh.sa[s*64+t2];
    tvloc[cnt++]=a;
    ws[OFF_TAGV+idx]=a;
  }
  __syncthreads();
  float* tagvs = sh.sa;
  cnt=0;
  for (int idx=tid; idx<TTAG*100; idx+=512) tagvs[idx]=tvloc[cnt++];
  __syncthreads();
  for (int idx=tid; idx<TTAG*100; idx+=512){
    int s=idx/100, k=idx%100;
    float a=0.f;
    #pragma unroll 10
    for (int h=0;h<100;h++) a += tagvs[s*100+h]*taw1[k*100+h];
    ws[OFF_TGW1+idx]=a;
  }
  for (int idx=tid; idx<TTAG*400; idx+=512){
    int s=idx/400, j=idx%400;
    const float* Wr = dWih + (size_t)j*332 + 200;
    float a=0.f;
    #pragma unroll 10
    for (int h=0;h<100;h++) a += tagvs[s*100+h]*Wr[h];
    ws[OFF_TGW+idx]=a;
  }
}

// ---------------- kMid: w1dt = enc @ attn_w1.T ----------------
__global__ void kMid(const float* aw1, float* ws){
  __shared__ float er[200];
  int n=blockIdx.x, tid=threadIdx.x;
  for (int i=tid;i<200;i+=128) er[i]=ws[OFF_ENC+n*200+i];
  __syncthreads();
  if (tid<100){
    const float* Wr = aw1 + tid*200;
    float a=0.f;
    #pragma unroll 8
    for (int d=0;d<200;d++) a += er[d]*Wr[d];
    ws[OFF_W1DT + n*100 + tid]=a;
  }
}

// ---------------- kDec: 1024-thread decoder, wave-local sync, 1-trip hc hop ----------------
__global__ __launch_bounds__(1024,1) void kDec(
    const float* dWhh, const float* dWih,
    const float* aw2, const float* aw3, const float* av,
    const float* taw2, const float* tav, float* ws)
{
  // padded strides: 101 per 100-wide row, 51 per 50-wide row (bank-conflict fix)
  __shared__ unsigned aw2L[100*101];
  __shared__ unsigned tw2L[100*101];
  __shared__ unsigned tw1L[TTAG*51];
  __shared__ unsigned tagvL[TTAG*51];
  __shared__ unsigned w1L[CHK*51];
  __shared__ unsigned encL[CHK*101];
  __shared__ float tavL[100], avL[100], aw3L[500];
  __shared__ float hL[100], cL[100], tcL[100], tsaL[100], nsL[200];
  __shared__ float uL[TTAG], tawL[TTAG];
  __shared__ float ctxL[200], a23L[100], ctxpL[200];
  __shared__ float srowL[CHK], eRL[CHK];
  __shared__ float sclL[GW];
  __shared__ float zOwnL[16];
  __shared__ float hdrL[4];
  __shared__ float prevL[5];
  __shared__ float MS[2];
  __shared__ int   amiL;

  const int tid = threadIdx.x;
  const int w   = blockIdx.x;
  unsigned long long* REC = (unsigned long long*)(ws + OFF_REC);
  unsigned long long* HC  = (unsigned long long*)(ws + OFF_HC);
  unsigned long long* FLG = (unsigned long long*)(ws + OFF_FLG);

  // ---- hidden-unit ownership: blocks 0..3 -> 4 units, 4..31 -> 3 units ----
  const int nu = (w<4)? 4 : 3;
  const int u0 = (w<4)? w*4 : 16 + (w-4)*3;
  const int nact = nu*4;
  const int jslot = tid>>5, l = tid&31;   // jslot<16 active (tid<512)

  // ---- tiny per-thread weight registers (own gate-rows only) ----
  unsigned wca0=0,wca1=0,wca2=0,wca3=0, wha0=0,wha1=0, wta0=0,wta1=0;
  int row=0;
  if (jslot < nact){
    row = (jslot&3)*100 + u0 + (jslot>>2);
    const float* Wr = dWih + (size_t)row*332;
    wca0=pk2(Wr[2*l],Wr[2*l+1]);
    wca1=pk2(Wr[2*(32+l)],Wr[2*(32+l)+1]);
    wca2=pk2(Wr[2*(64+l)],Wr[2*(64+l)+1]);
    if (l<4) wca3=pk2(Wr[2*(96+l)],Wr[2*(96+l)+1]);
    const float* Wh = dWhh + (size_t)row*100;
    wha0=pk2(Wh[2*l],Wh[2*l+1]);
    if (l<18) wha1=pk2(Wh[2*(32+l)],Wh[2*(32+l)+1]);
    const float* Wt = Wr + 200;
    wta0=pk2(Wt[2*l],Wt[2*l+1]);
    if (l<18) wta1=pk2(Wt[2*(32+l)],Wt[2*(32+l)+1]);
  }
  // ---- LDS preload (padded strides) ----
  for (int i=tid;i<100*100;i+=1024){ int k=i/100,p=i%100; aw2L[k*101+p]=pk2(aw2 [k*200+2*p], aw2 [k*200+2*p+1]); }
  for (int i=tid;i<100*100;i+=1024){ int k=i/100,p=i%100; tw2L[k*101+p]=pk2(taw2[k*200+2*p], taw2[k*200+2*p+1]); }
  for (int i=tid;i<TTAG*50;i+=1024){ int s=i/50,p=i%50; tw1L[s*51+p]=pk2(ws[OFF_TGW1+s*100+2*p], ws[OFF_TGW1+s*100+2*p+1]); }
  for (int i=tid;i<TTAG*50;i+=1024){ int s=i/50,p=i%50; tagvL[s*51+p]=pk2(ws[OFF_TAGV+s*100+2*p], ws[OFF_TAGV+s*100+2*p+1]); }
  for (int i=tid;i<CHK*50;i+=1024){ int r=i/50,p=i%50; w1L[r*51+p]=pk2(ws[OFF_W1DT+(w*CHK+r)*100+2*p], ws[OFF_W1DT+(w*CHK+r)*100+2*p+1]); }
  for (int i=tid;i<CHK*100;i+=1024){ int r=i/100,p=i%100; encL[r*101+p]=pk2(ws[OFF_ENC+(w*CHK+r)*200+2*p], ws[OFF_ENC+(w*CHK+r)*200+2*p+1]); }
  if (tid<100){ tavL[tid]=tav[tid]; avL[tid]=av[tid]; }
  for (int i=tid;i<500;i+=1024) aw3L[i]=aw3[i];
  if (tid<5)   prevL[tid]=0.f;
  if (tid<200) ctxL[tid]=ws[OFF_ENC + 2047*200 + tid];   // enc_last for init
  __syncthreads();

  // ---- init: own-row z0 -> h0,c0 -> publish hc (seq 1 embedded; 1 store) ----
  if (jslot < nact){
    float acc=0.f;
    { unsigned u=wca0; acc += ctxL[2*l]*blo(u) + ctxL[2*l+1]*bhi(u); }
    { unsigned u=wca1; acc += ctxL[2*(32+l)]*blo(u) + ctxL[2*(32+l)+1]*bhi(u); }
    { unsigned u=wca2; acc += ctxL[2*(64+l)]*blo(u) + ctxL[2*(64+l)+1]*bhi(u); }
    if (l<4){ unsigned u=wca3; acc += ctxL[2*(96+l)]*blo(u) + ctxL[2*(96+l)+1]*bhi(u); }
    acc += __shfl_xor(acc,1,32); acc += __shfl_xor(acc,2,32);
    acc += __shfl_xor(acc,4,32); acc += __shfl_xor(acc,8,32); acc += __shfl_xor(acc,16,32);
    if (l==0) zOwnL[jslot] = acc + ws[OFF_TGW + 63*400 + row] + ws[OFF_PEW + row];
  }
  __syncthreads();
  float cOwn = 0.f;   // own unit's cell state, f32, persists across steps (tid<nu)
  if (tid < nu){
    float zi=zOwnL[tid*4+0], zg=zOwnL[tid*4+2], zo=zOwnL[tid*4+3];
    float cc = sigf(zi)*tanhfast(zg);
    float hh = sigf(zo)*tanhfast(cc);
    cOwn = cc;
    ast64(HC + 128 + (u0+tid), (unsigned long long)pk2(hh,cc) | (1ull<<32));
  }

  for (int t=0; t<TLEN; ++t){
    const unsigned sq = (unsigned)(t+1);
    unsigned long long* slot = REC + (size_t)(t&1)*GW*RECU;
    unsigned long long* hcg  = HC + (size_t)((t+1)&1)*128;
    unsigned long long* hcp  = HC + (size_t)(t&1)*128;
    unsigned long long* fr   = FLG + (size_t)(t&1)*GW*16;

    // PH1: wave 0 lanes<50 poll+decode 2 seq-embedded hc words each (1 IC trip)
    if (tid < 50){
      const unsigned long long* p0 = hcg + 2*tid;
      unsigned long long v0, v1;
      for(;;){ v0=ald64(p0);   if((unsigned)(v0>>32)==sq) break; __builtin_amdgcn_s_sleep(1); }
      for(;;){ v1=ald64(p0+1); if((unsigned)(v1>>32)==sq) break; __builtin_amdgcn_s_sleep(1); }
      unsigned lo0=(unsigned)v0, lo1=(unsigned)v1;
      hL[2*tid]  =blo(lo0); cL[2*tid]  =bhi(lo0);
      hL[2*tid+1]=blo(lo1); cL[2*tid+1]=bhi(lo1);
    }
    __syncthreads();                                      // B1
    // PH2: tsa[k] = state · tag_attn_w2[k]   (8 thr/k, 13 guarded u64 each)
    if (tid<800){
      int k=tid>>3, q=tid&7;
      float acc=0.f;
      #pragma unroll
      for (int i=0;i<13;i++){
        int p=q*13+i;
        if (p<100){
          unsigned u=tw2L[k*101+p];
          const float* bp = (p<50)? &hL[2*p] : &cL[2*p-100];
          acc += bp[0]*blo(u) + bp[1]*bhi(u);
        }
      }
      acc += __shfl_xor(acc,1,8); acc += __shfl_xor(acc,2,8); acc += __shfl_xor(acc,4,8);
      if (q==0) tsaL[k]=acc;
    }
    __syncthreads();                                      // B2
    { // PH3: tag scores (16 thr/tag)
      int sp=tid>>4, l16=tid&15;
      float acc=0.f;
      #pragma unroll
      for (int i=0;i<7;i++){
        int k=l16+16*i;
        if (k<100){
          unsigned u=tw1L[sp*51+(k>>1)];
          float w1v=(k&1)? bhi(u) : blo(u);
          acc += tanhfast(w1v + tsaL[k]) * tavL[k];
        }
      }
      acc += __shfl_xor(acc,1,16); acc += __shfl_xor(acc,2,16);
      acc += __shfl_xor(acc,4,16); acc += __shfl_xor(acc,8,16);
      if (l16==0) uL[sp]=acc;
    }
    __syncthreads();                                      // B3
    if (tid<64){ // PH4: softmax over 64 tags
      float v=uL[tid], m=v;
      for (int d=1;d<64;d<<=1) m=fmaxf(m,__shfl_xor(m,d,64));
      float e=__expf(v-m), ssum=e;
      for (int d=1;d<64;d<<=1) ssum+=__shfl_xor(ssum,d,64);
      tawL[tid]=e*rcpf(ssum);
    }
    __syncthreads();                                      // B4
    if (tid<800){ // PH5: tag_ctx (8 thr/hh) + fold ns
      int hh=tid>>3, q=tid&7;
      float acc=0.f;
      #pragma unroll
      for (int i=0;i<8;i++){
        int s=q*8+i;
        unsigned u=tagvL[s*51+(hh>>1)];
        acc += tawL[s]*((hh&1)? bhi(u):blo(u));
      }
      acc += __shfl_xor(acc,1,8); acc += __shfl_xor(acc,2,8); acc += __shfl_xor(acc,4,8);
      if (q==0){ tcL[hh]=acc; nsL[hh]=hL[hh]+acc; nsL[100+hh]=cL[hh]+acc; }
    }
    __syncthreads();                                      // B5
    if (tid<800){ // PH6: a23[k] (8 thr/k, 13 guarded u64 each)
      int k=tid>>3, q=tid&7;
      float acc=0.f;
      #pragma unroll
      for (int i=0;i<13;i++){
        int p=q*13+i;
        if (p<100){
          unsigned u=aw2L[k*101+p];
          acc += nsL[2*p]*blo(u) + nsL[2*p+1]*bhi(u);
        }
      }
      acc += __shfl_xor(acc,1,8); acc += __shfl_xor(acc,2,8); acc += __shfl_xor(acc,4,8);
      if (q==0){
        float a3=0.f;
        #pragma unroll
        for (int i=0;i<5;i++) a3 += prevL[i]*aw3L[k*5+i];
        a23L[k]=acc+a3;
      }
    }
    __syncthreads();                                      // B6
    { // PH7: own 64 rows' scores (16 lanes/row)
      int r=tid>>4, l16=tid&15;
      float acc=0.f;
      #pragma unroll
      for (int i=0;i<7;i++){
        int k=l16+16*i;
        if (k<100){
          unsigned u=w1L[r*51+(k>>1)];
          float w1v=(k&1)? bhi(u) : blo(u);
          acc += tanhfast(w1v + a23L[k]) * avL[k];
        }
      }
      acc += __shfl_xor(acc,1,16); acc += __shfl_xor(acc,2,16);
      acc += __shfl_xor(acc,4,16); acc += __shfl_xor(acc,8,16);
      if (l16==0) srowL[r]=acc;
    }
    __syncthreads();                                      // B7
    if (tid<64){ // PH8: local stats + argmax over own 64 rows
      float v=srowL[tid], m=v;
      for (int d=1;d<64;d<<=1) m=fmaxf(m,__shfl_xor(m,d,64));
      float e=__expf(v-m); eRL[tid]=e;
      float Ss=e;
      for (int d=1;d<64;d<<=1) Ss+=__shfl_xor(Ss,d,64);
      float bv=v; int bi=w*CHK+tid;
      for (int d=1;d<64;d<<=1){
        float ov=__shfl_xor(bv,d,64); int oi=__shfl_xor(bi,d,64);
        if (ov>bv || (ov==bv && oi<bi)){ bv=ov; bi=oi; }
      }
      if (tid==0){ hdrL[0]=m; hdrL[1]=Ss; hdrL[2]=bv; ((int*)hdrL)[3]=bi; }
    }
    __syncthreads();                                      // B8
    if (tid<800){ // PH9: ctx partial over own rows (4 thr/d, 16 rows each)
      int d=tid>>2, q=tid&3;
      float acc=0.f;
      #pragma unroll
      for (int i=0;i<16;i++){
        int rr=q*16+i;
        unsigned u=encL[rr*101+(d>>1)];
        acc += eRL[rr]*((d&1)? bhi(u):blo(u));
      }
      acc += __shfl_xor(acc,1,4); acc += __shfl_xor(acc,2,4);
      if (q==0) ctxpL[d]=acc;
    }
    __syncthreads();                                      // B9

    // PH10/11: wave 15 publishes record (wave-local vm0+flag);
    //          tid<512 concurrently compute their zpre rows.
    if (tid < 512){
      if (jslot < nact){
        float acc=0.f;
        { unsigned u=wha0; acc += hL[2*l]*blo(u) + hL[2*l+1]*bhi(u); }
        if (l<18){ unsigned u=wha1; acc += hL[2*(32+l)]*blo(u) + hL[2*(32+l)+1]*bhi(u); }
        { unsigned u=wta0; acc += tcL[2*l]*blo(u) + tcL[2*l+1]*bhi(u); }
        if (l<18){ unsigned u=wta1; acc += tcL[2*(32+l)]*blo(u) + tcL[2*(32+l)+1]*bhi(u); }
        acc += __shfl_xor(acc,1,32); acc += __shfl_xor(acc,2,32);
        acc += __shfl_xor(acc,4,32); acc += __shfl_xor(acc,8,32); acc += __shfl_xor(acc,16,32);
        if (l==0) zOwnL[jslot] = acc + ws[OFF_PEW + t*400 + row];
      }
    } else if (tid >= 960){
      int lane = tid-960;
      unsigned long long* rp = slot + (size_t)w*RECU;
      if (lane < 50)
        ast64(rp+lane, (unsigned long long)pk2(ctxpL[4*lane],ctxpL[4*lane+1])
                     | ((unsigned long long)pk2(ctxpL[4*lane+2],ctxpL[4*lane+3])<<32));
      else { int j=lane-50;  // j=0..13 -> words 50..63
        ast64(rp+lane, (unsigned long long)pk2(srowL[4*j],srowL[4*j+1])
                     | ((unsigned long long)pk2(srowL[4*j+2],srowL[4*j+3])<<32)); }
      if (lane < 2){ int j=14+lane;  // words 64,65
        ast64(rp+64+lane, (unsigned long long)pk2(srowL[4*j],srowL[4*j+1])
                        | ((unsigned long long)pk2(srowL[4*j+2],srowL[4*j+3])<<32)); }
      else if (lane==2)
        ast64(rp+66, (unsigned long long)__float_as_uint(hdrL[0])
                   | ((unsigned long long)__float_as_uint(hdrL[1])<<32));
      else if (lane==3)
        ast64(rp+67, (unsigned long long)__float_as_uint(hdrL[2])
                   | ((unsigned long long)(unsigned)((int*)hdrL)[3]<<32));
      vm0();
      if (lane==0) ast64(fr + (size_t)w*16, (unsigned long long)sq);
    }

    // PH12: wave 0 polls record flags (__all); single release barrier
    if (tid < 64){
      int ok = (tid >= GW) ? 1 : 0;
      for(;;){
        if (!ok) ok = ((unsigned)ald64(fr + (size_t)tid*16) == sq);
        if (__all(ok)) break;
      }
    }
    __syncthreads();                                      // B10
    // PH13: tid<800 bulk-read ctx words (2 recs each); wave 15 hdr + reduce
    unsigned long long pay[2];
    if (tid<800){
      int dw=tid>>4, s16=tid&15;
      pay[0]=ald64(slot + (size_t)(s16*2  )*RECU + dw);
      pay[1]=ald64(slot + (size_t)(s16*2+1)*RECU + dw);
    } else if (tid>=960){
      int lane=tid-960, r=lane&31, up=lane>>5;
      unsigned long long v = ald64(slot + (size_t)r*RECU + 66 + up);
      float x0 = __uint_as_float((unsigned)v);
      float x1 = __uint_as_float((unsigned)(v>>32));
      int   xi = (int)(unsigned)(v>>32);
      float pv = x0; int pi = xi;
      #pragma unroll
      for (int d=1;d<32;d<<=1){
        float ov=__shfl_xor(pv,d,32); int oi=__shfl_xor(pi,d,32);
        if (up){ if (ov>pv || (ov==pv && oi<pi)){ pv=ov; pi=oi; } }
        else   { pv = fmaxf(pv,ov); }
      }
      if (!up){
        float sc = __expf(x0 - pv);                       // pv = M
        sclL[r] = sc;
        float ss = sc * x1;
        #pragma unroll
        for (int d=1;d<32;d<<=1) ss += __shfl_xor(ss,d,32);
        if (r==0){ MS[0]=pv; MS[1]=ss; }
      } else {
        if (r==0) amiL = pi;
      }
    }
    __syncthreads();                                      // B11
    // PH15b: ctx assemble (16-lane groups, 2 recs each)
    if (tid<800){
      float rS = rcpf(MS[1]);
      int dw=tid>>4, s16=tid&15;
      float c0=0.f,c1=0.f,c2=0.f,c3=0.f;
      #pragma unroll
      for (int i=0;i<2;i++){
        float sc=sclL[s16*2+i];
        unsigned lo=(unsigned)pay[i], hi=(unsigned)(pay[i]>>32);
        c0 += blo(lo)*sc; c1 += bhi(lo)*sc;
        c2 += blo(hi)*sc; c3 += bhi(hi)*sc;
      }
      #pragma unroll
      for (int d=1;d<16;d<<=1){
        c0 += __shfl_xor(c0,d,16); c1 += __shfl_xor(c1,d,16);
        c2 += __shfl_xor(c2,d,16); c3 += __shfl_xor(c3,d,16);
      }
      if (s16==0){
        ctxL[4*dw+0]=c0*rS; ctxL[4*dw+1]=c1*rS;
        ctxL[4*dw+2]=c2*rS; ctxL[4*dw+3]=c3*rS;
      }
    }
    __syncthreads();                                      // B12
    // PH16: own-row z += ctx·Wihc
    if (jslot < nact){
      float acc=0.f;
      { unsigned u=wca0; acc += ctxL[2*l]*blo(u) + ctxL[2*l+1]*bhi(u); }
      { unsigned u=wca1; acc += ctxL[2*(32+l)]*blo(u) + ctxL[2*(32+l)+1]*bhi(u); }
      { unsigned u=wca2; acc += ctxL[2*(64+l)]*blo(u) + ctxL[2*(64+l)+1]*bhi(u); }
      if (l<4){ unsigned u=wca3; acc += ctxL[2*(96+l)]*blo(u) + ctxL[2*(96+l)+1]*bhi(u); }
      acc += __shfl_xor(acc,1,32); acc += __shfl_xor(acc,2,32);
      acc += __shfl_xor(acc,4,32); acc += __shfl_xor(acc,8,32); acc += __shfl_xor(acc,16,32);
      if (l==0) zOwnL[jslot] += acc;
    }
    __syncthreads();                                      // B13
    // PH15a: next-step prev window (5 system loads; overlaps PH17 + hc hop).
    // slot/MS/amiL stable until next step's B10/B11; prevL consumed next PH6.
    if (tid>=440 && tid<445){
      int i=tid-440;
      int st = amiL-1; st = st<0?0:st; st = st>NN-6?NN-6:st;
      int g = st+i, r=g>>6, lr=g&63;
      unsigned long long v = ald64(slot + (size_t)r*RECU + 50 + (lr>>2));
      unsigned half = (lr&2)? (unsigned)(v>>32) : (unsigned)v;
      float sc = (lr&1)? bhi(half) : blo(half);
      prevL[i] = __expf(sc - MS[0]) * rcpf(MS[1]);
    }
    // PH17: own-unit gates (f32 own state); single seq-embedded hc store
    if (tid < nu){
      float zi=zOwnL[tid*4+0], zf=zOwnL[tid*4+1], zg=zOwnL[tid*4+2], zo=zOwnL[tid*4+3];
      float cc = sigf(zf)*cOwn + sigf(zi)*tanhfast(zg);
      float hh = sigf(zo)*tanhfast(cc);
      cOwn = cc;
      ast64(hcp + (u0+tid), (unsigned long long)pk2(hh,cc)
                          | ((unsigned long long)(sq+1)<<32));
      ws[OFF_HOUT + t*100 + (u0+tid)] = hh;
    }
    // next iteration's PH1 poll + B1 is the inter-step sync
  }
}

// ---------------- kLoss: parallel logits + log-softmax over V ----------------
__global__ __launch_bounds__(256) void kLoss(const float* outW, const float* outb,
                                             const int* oid, float* ws)
{
  const int b=blockIdx.x, tid=threadIdx.x;
  const int tile=b>>1, hf=b&1, t0=tile*16;
  __shared__ float s_hn[16*100];
  __shared__ int   s_oid[16];
  __shared__ float red[4][16][3];
  for (int i=tid;i<1600;i+=256) s_hn[i]=ws[OFF_HOUT + t0*100 + i];
  if (tid<16) s_oid[tid]=oid[t0+tid];
  __syncthreads();
  const int VSPLIT = 25129;
  int vbeg = hf? VSPLIT : 0;
  int vend = hf? VOC : VSPLIT;
  float rm[16], rs[16], ol[16];
  #pragma unroll
  for (int tt=0;tt<16;tt++){ rm[tt]=-1e30f; rs[tt]=0.f; ol[tt]=-1e30f; }
  for (int v=vbeg+tid; v<vend; v+=256){
    const float4* wr = (const float4*)(outW + (size_t)v*100);
    float acc[16];
    #pragma unroll
    for (int tt=0;tt<16;tt++) acc[tt]=0.f;
    #pragma unroll 5
    for (int q=0;q<25;q++){
      float4 wv = wr[q];
      #pragma unroll
      for (int tt=0;tt<16;tt++){
        float4 hv = *(const float4*)(s_hn + tt*100 + q*4);
        acc[tt] += wv.x*hv.x + wv.y*hv.y + wv.z*hv.z + wv.w*hv.w;
      }
    }
    float bb = outb[v];
    #pragma unroll
    for (int tt=0;tt<16;tt++){
      float lg = acc[tt] + bb;
      if (v == s_oid[tt]) ol[tt] = fmaxf(ol[tt], lg);
      if (lg <= rm[tt]) rs[tt] += __expf(lg - rm[tt]);
      else { rs[tt] = rs[tt]*__expf(rm[tt]-lg) + 1.0f; rm[tt]=lg; }
    }
  }
  int wv2=tid>>6, ln=tid&63;
  #pragma unroll
  for (int tt=0;tt<16;tt++){
    float m=rm[tt], sv=rs[tt], o=ol[tt];
    for (int d=1;d<64;d<<=1){
      float om=__shfl_xor(m,d,64), os=__shfl_xor(sv,d,64), oo=__shfl_xor(o,d,64);
      float M2=fmaxf(m,om);
      sv = sv*__expf(m-M2) + os*__expf(om-M2);
      m=M2; o=fmaxf(o,oo);
    }
    if (ln==0){ red[wv2][tt][0]=m; red[wv2][tt][1]=sv; red[wv2][tt][2]=o; }
  }
  __syncthreads();
  if (tid<16){
    float M=-1e30f;
    for (int q=0;q<4;q++) M=fmaxf(M,red[q][tid][0]);
    float S=0.f, O=-1e30f;
    for (int q=0;q<4;q++){ S += red[q][tid][1]*__expf(red[q][tid][0]-M); O=fmaxf(O,red[q][tid][2]); }
    float* pb = ws + OFF_PB + (((tile*2)+hf)*16 + tid)*4;
    pb[0]=M; pb[1]=S; pb[2]=O;
  }
}

// ---------------- kFinal: combine halves, sum, scale ----------------
__global__ void kFinal(const float* weight, float* ws, float* out){
  __shared__ float red[256];
  int tid=threadIdx.x;
  float acc=0.f;
  for (int t=tid;t<TLEN;t+=256){
    int tile=t>>4, tt=t&15;
    const float* p0 = ws + OFF_PB + ((tile*2+0)*16+tt)*4;
    const float* p1 = ws + OFF_PB + ((tile*2+1)*16+tt)*4;
    float M=fmaxf(p0[0],p1[0]);
    float S=p0[1]*__expf(p0[0]-M) + p1[1]*__expf(p1[0]-M);
    float O=fmaxf(p0[2],p1[2]);
    acc += (M + logf(S)) - O;
  }
  red[tid]=acc; __syncthreads();
  for (int d=128; d>0; d>>=1){
    if (tid<d) red[tid]+=red[tid+d];
    __syncthreads();
  }
  if (tid==0) out[0]=red[0]*weight[0];
}

// ---------------- launch ----------------
extern "C" void kernel_launch(void* const* d_in, const int* in_sizes, int n_in,
                              void* d_out, int out_size, void* d_ws, size_t ws_size,
                              hipStream_t stream) {
  const int*   src      = (const int*)  d_in[0];
  const int*   tag      = (const int*)  d_in[1];
  const int*   oid      = (const int*)  d_in[2];
  const float* weight   = (const float*)d_in[3];
  const float* emb_char = (const float*)d_in[4];
  const float* emb_tag  = (const float*)d_in[5];
  const float* fWih=(const float*)d_in[6],  *fWhh=(const float*)d_in[7],  *fb=(const float*)d_in[8];
  const float* bWih=(const float*)d_in[9],  *bWhh=(const float*)d_in[10], *bb=(const float*)d_in[11];
  const float* tWih=(const float*)d_in[12], *tWhh=(const float*)d_in[13], *tb=(const float*)d_in[14];
  const float* dWih=(const float*)d_in[15], *dWhh=(const float*)d_in[16], *db=(const float*)d_in[17];
  const float* aw1 =(const float*)d_in[18], *aw2=(const float*)d_in[19];
  const float* aw3 =(const float*)d_in[20], *av =(const float*)d_in[21];
  const float* taw1=(const float*)d_in[22], *taw2=(const float*)d_in[23], *tavv=(const float*)d_in[24];
  const float* outW=(const float*)d_in[25], *outb=(const float*)d_in[26];
  float* ws  = (float*)d_ws;
  float* out = (float*)d_out;

  kInit<<<8, 256, 0, stream>>>(ws);
  kPrep<<<2*NN+TTAG+TLEN, 512, 0, stream>>>(src,tag,oid,emb_char,emb_tag,
                                            fWih,fb,bWih,bb,tWih,tb,dWih,db,ws);
  kEnc<<<3,512,0,stream>>>(fWhh,bWhh,tWhh,taw1,dWih,ws);
  kMid<<<NN,128,0,stream>>>(aw1,ws);
  kDec<<<GW,1024,0,stream>>>(dWhh,dWih,aw2,aw3,av,taw2,tavv,ws);
  kLoss<<<256,256,0,stream>>>(outW,outb,oid,ws);
  kFinal<<<1,256,0,stream>>>(weight,ws,out);
}

// Round 12
// 25914.682 us; speedup vs baseline: 1.1737x; 1.1737x over previous
//
#include <hip/hip_runtime.h>
#include <math.h>

// ---------------- problem sizes ----------------
#define NN   2048   // source length
#define TLEN 2048   // target length
#define TTAG 64     // tags
#define VOC  50257
#define GW   32     // decoder blocks; each owns CHK source rows + 3-4 hidden units
#define CHK  64     // source rows per block
#define RECU 80     // u64 stride per record (68 used)
static_assert(GW * CHK == NN, "chunking");

// ---------------- workspace layout (float units) ----------------
#define OFF_XF    0                          // NN*400
#define OFF_XB    (OFF_XF  + NN*400)         // NN*400
#define OFF_TGX   (OFF_XB  + NN*400)         // TTAG*400
#define OFF_PEW   (OFF_TGX + TTAG*400)       // TLEN*400
#define OFF_ENC   (OFF_PEW + TLEN*400)       // NN*200
#define OFF_W1DT  (OFF_ENC + NN*200)         // NN*100
#define OFF_TAGV  (OFF_W1DT+ NN*100)         // TTAG*100
#define OFF_TGW1  (OFF_TAGV+ TTAG*100)       // TTAG*100
#define OFF_TGW   (OFF_TGW1+ TTAG*100)       // TTAG*400
#define OFF_HOUT  (OFF_TGW + TTAG*400)       // TLEN*100
#define OFF_REC   (OFF_HOUT+ TLEN*100)       // 2*GW*RECU u64
#define OFF_HC    (OFF_REC + 2*GW*RECU*2)    // 2*128 u64 (seq-embedded h/c words)
#define OFF_FLG   (OFF_HC  + 2*128*2)        // 2048 u64 flags (128B-spread)
#define OFF_PB    (OFF_FLG + 4096)           // loss partials

// record u64 words: [0..49] ctxp 4xbf16/word, [50..65] scores 4xbf16/word (64 rows),
//   [66]={m f32 | S f32}, [67]={amax f32 | idx}
// SPLIT publish: words 50..67 + flag fh after PH8; words 0..49 + flag fr after PH9.
// hc buffer b: word u = { h bf16 | c bf16 | seq u32 }  (single-trip, seq-embedded)
// flags: fr slots [(t&1)*GW + w], fh slots [64 + (t&1)*GW + w]; value = seq.

// ---------------- helpers ----------------
__device__ __forceinline__ float rcpf(float x){ return __builtin_amdgcn_rcpf(x); }
__device__ __forceinline__ float sigf(float x){ return rcpf(1.0f+__expf(-x)); }
__device__ __forceinline__ float tanhfast(float x){
  float e = __expf(2.0f*x);
  return 1.0f - 2.0f*rcpf(e+1.0f);
}
__device__ __forceinline__ unsigned short f2b(float x){
  unsigned b=__float_as_uint(x);
  return (unsigned short)((b + 0x7fffu + ((b>>16)&1u))>>16);
}
__device__ __forceinline__ unsigned pk2(float a,float b){ return (unsigned)f2b(a) | ((unsigned)f2b(b)<<16); }
__device__ __forceinline__ float blo(unsigned u){ return __uint_as_float(u<<16); }
__device__ __forceinline__ float bhi(unsigned u){ return __uint_as_float(u&0xffff0000u); }

__device__ __forceinline__ unsigned long long ald64(const unsigned long long* p){
  return __hip_atomic_load(p,__ATOMIC_RELAXED,__HIP_MEMORY_SCOPE_SYSTEM);
}
__device__ __forceinline__ void ast64(unsigned long long* p, unsigned long long v){
  __hip_atomic_store(p,v,__ATOMIC_RELAXED,__HIP_MEMORY_SCOPE_SYSTEM);
}
__device__ __forceinline__ void vm0(){ asm volatile("s_waitcnt vmcnt(0)" ::: "memory"); }

// ---------------- kInit: zero flag region (every launch / replay) ----------------
__global__ void kInit(float* ws){
  unsigned long long* f = (unsigned long long*)(ws + OFF_FLG);
  int i = blockIdx.x*256 + threadIdx.x;
  if (i < 2048) ast64(f+i, 0ull);
}

// ---------------- kPrep: all input-side GEMVs (parallel) ----------------
__global__ __launch_bounds__(512) void kPrep(
    const int* src, const int* tag, const int* oid,
    const float* emb_char, const float* emb_tag,
    const float* fWih, const float* fb,
    const float* bWih, const float* bb,
    const float* tWih, const float* tb,
    const float* dWih, const float* db, float* ws)
{
  int r = blockIdx.x, j = threadIdx.x;
  if (j >= 400) return;
  if (r < NN) {
    const float* e = emb_char + (size_t)src[r]*32;
    const float* Wr = fWih + j*32;
    float a = fb[j];
    #pragma unroll
    for (int q=0;q<32;q++) a += e[q]*Wr[q];
    ws[OFF_XF + r*400 + j] = a;
  } else if (r < 2*NN) {
    int n = r - NN;
    const float* e = emb_char + (size_t)src[n]*32;
    const float* Wr = bWih + j*32;
    float a = bb[j];
    #pragma unroll
    for (int q=0;q<32;q++) a += e[q]*Wr[q];
    ws[OFF_XB + n*400 + j] = a;
  } else if (r < 2*NN + TTAG) {
    int s = r - 2*NN;
    const float* e = emb_tag + (size_t)tag[s]*32;
    const float* Wr = tWih + j*32;
    float a = tb[j];
    #pragma unroll
    for (int q=0;q<32;q++) a += e[q]*Wr[q];
    ws[OFF_TGX + s*400 + j] = a;
  } else {
    int t = r - (2*NN + TTAG);
    int pid = (t==0) ? 0 : oid[t-1];
    const float* e = emb_char + (size_t)pid*32;
    const float* Wr = dWih + (size_t)j*332 + 300;
    float a = db[j];
    #pragma unroll
    for (int q=0;q<32;q++) a += e[q]*Wr[q];
    ws[OFF_PEW + t*400 + j] = a;
  }
}

// ---------------- kEnc: sequential LSTM scans (3 independent blocks) ----------------
// z-loops FULLY unrolled so whh[100] stays in VGPRs.
struct EncShared {
  float tvs[TTAG*100];
  float sa [TTAG*64];
  float hbuf[100];
  float zbuf[400];
};

__device__ void lstm_block(const float* Whh, const float* xbase, float* ws,
                           int reverse, int col, EncShared* sh)
{
  int tid = threadIdx.x;
  float whh[100];
  if (tid < 400){
    #pragma unroll
    for (int k=0;k<100;k++) whh[k] = Whh[tid*100+k];
  }
  float c = 0.f;
  if (tid < 100) sh->hbuf[tid] = 0.f;
  __syncthreads();
  for (int i=0;i<NN;i++){
    int n = reverse ? (NN-1-i) : i;
    if (tid < 400){
      float z = xbase[n*400+tid];
      #pragma unroll
      for (int k=0;k<100;k++) z += whh[k]*sh->hbuf[k];
      sh->zbuf[tid] = z;
    }
    __syncthreads();
    if (tid < 100){
      float zi=sh->zbuf[tid], zf=sh->zbuf[tid+100], zg=sh->zbuf[tid+200], zo=sh->zbuf[tid+300];
      c = sigf(zf)*c + sigf(zi)*tanhfast(zg);
      float h = sigf(zo)*tanhfast(c);
      sh->hbuf[tid] = h;
      ws[OFF_ENC + n*200 + col + tid] = h;
    }
    __syncthreads();
  }
}

__global__ __launch_bounds__(512,1) void kEnc(
    const float* fWhh, const float* bWhh, const float* tWhh,
    const float* taw1, const float* dWih, float* ws)
{
  __shared__ EncShared sh;
  int b = blockIdx.x, tid = threadIdx.x;
  if (b == 0){ lstm_block(fWhh, ws+OFF_XF, ws, 0, 0,   &sh); return; }
  if (b == 1){ lstm_block(bWhh, ws+OFF_XB, ws, 1, 100, &sh); return; }

  // ---- block 2: tag LSTM + self-attn + tagv-derived tables ----
  {
    float whh[100];
    if (tid<400){
      #pragma unroll
      for (int k=0;k<100;k++) whh[k] = tWhh[tid*100+k];
    }
    float c = 0.f;
    if (tid<100) sh.hbuf[tid] = 0.f;
    __syncthreads();
    for (int s=0;s<TTAG;s++){
      if (tid<400){
        float z = ws[OFF_TGX + s*400 + tid];
        #pragma unroll
        for (int k=0;k<100;k++) z += whh[k]*sh.hbuf[k];
        sh.zbuf[tid] = z;
      }
      __syncthreads();
      if (tid<100){
        float zi=sh.zbuf[tid], zf=sh.zbuf[tid+100], zg=sh.zbuf[tid+200], zo=sh.zbuf[tid+300];
        c = sigf(zf)*c + sigf(zi)*tanhfast(zg);
        float h = sigf(zo)*tanhfast(c);
        sh.hbuf[tid] = h;
        sh.tvs[s*100+tid] = h;
      }
      __syncthreads();
    }
  }
  for (int idx=tid; idx<TTAG*TTAG; idx+=512){
    int s=idx>>6, t2=idx&63;
    float a=0.f;
    #pragma unroll 10
    for (int h=0;h<100;h++) a += sh.tvs[s*100+h]*sh.tvs[t2*100+h];
    sh.sa[idx]=a;
  }
  __syncthreads();
  if (tid<TTAG){
    float m=-1e30f;
    for (int t2=0;t2<64;t2++) m = fmaxf(m, sh.sa[tid*64+t2]);
    float sum=0.f;
    for (int t2=0;t2<64;t2++){ float e=__expf(sh.sa[tid*64+t2]-m); sh.sa[tid*64+t2]=e; sum+=e; }
    float r=1.f/sum;
    for (int t2=0;t2<64;t2++) sh.sa[tid*64+t2]*=r;
  }
  __syncthreads();
  float tvloc[13]; int cnt=0;
  for (int idx=tid; idx<TTAG*100; idx+=512){
    int t2=idx/100, hh=idx%100;
    float a = sh.tvs[t2*100+hh];
    for (int s=0;s<64;s++) a += sh.tvs[s*100+hh]*sh.sa[s*64+t2];
    tvloc[cnt++]=a;
    ws[OFF_TAGV+idx]=a;
  }
  __syncthreads();
  float* tagvs = sh.sa;
  cnt=0;
  for (int idx=tid; idx<TTAG*100; idx+=512) tagvs[idx]=tvloc[cnt++];
  __syncthreads();
  for (int idx=tid; idx<TTAG*100; idx+=512){
    int s=idx/100, k=idx%100;
    float a=0.f;
    #pragma unroll 10
    for (int h=0;h<100;h++) a += tagvs[s*100+h]*taw1[k*100+h];
    ws[OFF_TGW1+idx]=a;
  }
  for (int idx=tid; idx<TTAG*400; idx+=512){
    int s=idx/400, j=idx%400;
    const float* Wr = dWih + (size_t)j*332 + 200;
    float a=0.f;
    #pragma unroll 10
    for (int h=0;h<100;h++) a += tagvs[s*100+h]*Wr[h];
    ws[OFF_TGW+idx]=a;
  }
}

// ---------------- kMid: w1dt = enc @ attn_w1.T ----------------
__global__ void kMid(const float* aw1, float* ws){
  __shared__ float er[200];
  int n=blockIdx.x, tid=threadIdx.x;
  for (int i=tid;i<200;i+=128) er[i]=ws[OFF_ENC+n*200+i];
  __syncthreads();
  if (tid<100){
    const float* Wr = aw1 + tid*200;
    float a=0.f;
    #pragma unroll 8
    for (int d=0;d<200;d++) a += er[d]*Wr[d];
    ws[OFF_W1DT + n*100 + tid]=a;
  }
}

// ---------------- kDec: 512-thread decoder, 1-trip hc, split record publish ----------------
__global__ __launch_bounds__(512) void kDec(
    const float* dWhh, const float* dWih,
    const float* aw2, const float* aw3, const float* av,
    const float* taw2, const float* tav, float* ws)
{
  // padded strides: 101 per 100-wide row, 51 per 50-wide row (bank-conflict fix)
  __shared__ unsigned aw2L[100*101];
  __shared__ unsigned tw2L[100*101];
  __shared__ unsigned tw1L[TTAG*51];
  __shared__ unsigned tagvL[TTAG*51];
  __shared__ unsigned w1L[CHK*51];
  __shared__ unsigned encL[CHK*101];
  __shared__ float tavL[100], avL[100], aw3L[500];
  __shared__ float hL[100], cL[100], tcL[100], tsaL[100], nsL[200];
  __shared__ float uL[TTAG], tawL[TTAG];
  __shared__ float ctxL[200], a23L[100], ctxpL[200];
  __shared__ float srowL[CHK], eRL[CHK];
  __shared__ float sclL[GW];
  __shared__ float zOwnL[16];
  __shared__ float hdrL[4];
  __shared__ float prevL[5];
  __shared__ float MS[2];
  __shared__ int   amiL;

  const int tid = threadIdx.x;
  const int w   = blockIdx.x;
  unsigned long long* REC = (unsigned long long*)(ws + OFF_REC);
  unsigned long long* HC  = (unsigned long long*)(ws + OFF_HC);
  unsigned long long* FLG = (unsigned long long*)(ws + OFF_FLG);

  // ---- hidden-unit ownership: blocks 0..3 -> 4 units, 4..31 -> 3 units ----
  const int nu = (w<4)? 4 : 3;
  const int u0 = (w<4)? w*4 : 16 + (w-4)*3;
  const int nact = nu*4;
  const int jslot = tid>>5, l = tid&31;

  // ---- tiny per-thread weight registers (own gate-rows only) ----
  unsigned wca0=0,wca1=0,wca2=0,wca3=0, wha0=0,wha1=0, wta0=0,wta1=0;
  int row=0;
  if (jslot < nact){
    row = (jslot&3)*100 + u0 + (jslot>>2);
    const float* Wr = dWih + (size_t)row*332;
    wca0=pk2(Wr[2*l],Wr[2*l+1]);
    wca1=pk2(Wr[2*(32+l)],Wr[2*(32+l)+1]);
    wca2=pk2(Wr[2*(64+l)],Wr[2*(64+l)+1]);
    if (l<4) wca3=pk2(Wr[2*(96+l)],Wr[2*(96+l)+1]);
    const float* Wh = dWhh + (size_t)row*100;
    wha0=pk2(Wh[2*l],Wh[2*l+1]);
    if (l<18) wha1=pk2(Wh[2*(32+l)],Wh[2*(32+l)+1]);
    const float* Wt = Wr + 200;
    wta0=pk2(Wt[2*l],Wt[2*l+1]);
    if (l<18) wta1=pk2(Wt[2*(32+l)],Wt[2*(32+l)+1]);
  }
  // ---- LDS preload (padded strides) ----
  for (int i=tid;i<100*100;i+=512){ int k=i/100,p=i%100; aw2L[k*101+p]=pk2(aw2 [k*200+2*p], aw2 [k*200+2*p+1]); }
  for (int i=tid;i<100*100;i+=512){ int k=i/100,p=i%100; tw2L[k*101+p]=pk2(taw2[k*200+2*p], taw2[k*200+2*p+1]); }
  for (int i=tid;i<TTAG*50;i+=512){ int s=i/50,p=i%50; tw1L[s*51+p]=pk2(ws[OFF_TGW1+s*100+2*p], ws[OFF_TGW1+s*100+2*p+1]); }
  for (int i=tid;i<TTAG*50;i+=512){ int s=i/50,p=i%50; tagvL[s*51+p]=pk2(ws[OFF_TAGV+s*100+2*p], ws[OFF_TAGV+s*100+2*p+1]); }
  for (int i=tid;i<CHK*50;i+=512){ int r=i/50,p=i%50; w1L[r*51+p]=pk2(ws[OFF_W1DT+(w*CHK+r)*100+2*p], ws[OFF_W1DT+(w*CHK+r)*100+2*p+1]); }
  for (int i=tid;i<CHK*100;i+=512){ int r=i/100,p=i%100; encL[r*101+p]=pk2(ws[OFF_ENC+(w*CHK+r)*200+2*p], ws[OFF_ENC+(w*CHK+r)*200+2*p+1]); }
  if (tid<100){ tavL[tid]=tav[tid]; avL[tid]=av[tid]; }
  for (int i=tid;i<500;i+=512) aw3L[i]=aw3[i];
  if (tid<5)   prevL[tid]=0.f;
  if (tid<200) ctxL[tid]=ws[OFF_ENC + 2047*200 + tid];   // enc_last for init
  __syncthreads();

  // ---- init: own-row z0 -> h0,c0 -> publish hc (seq-embedded, single store) ----
  if (jslot < nact){
    float acc=0.f;
    { unsigned u=wca0; acc += ctxL[2*l]*blo(u) + ctxL[2*l+1]*bhi(u); }
    { unsigned u=wca1; acc += ctxL[2*(32+l)]*blo(u) + ctxL[2*(32+l)+1]*bhi(u); }
    { unsigned u=wca2; acc += ctxL[2*(64+l)]*blo(u) + ctxL[2*(64+l)+1]*bhi(u); }
    if (l<4){ unsigned u=wca3; acc += ctxL[2*(96+l)]*blo(u) + ctxL[2*(96+l)+1]*bhi(u); }
    acc += __shfl_xor(acc,1,32); acc += __shfl_xor(acc,2,32);
    acc += __shfl_xor(acc,4,32); acc += __shfl_xor(acc,8,32); acc += __shfl_xor(acc,16,32);
    if (l==0) zOwnL[jslot] = acc + ws[OFF_TGW + 63*400 + row] + ws[OFF_PEW + row];
  }
  __syncthreads();
  float cOwn = 0.f;   // own unit's cell state, f32, persists across steps (tid<nu)
  if (tid < nu){
    float zi=zOwnL[tid*4+0], zg=zOwnL[tid*4+2], zo=zOwnL[tid*4+3];
    float cc = sigf(zi)*tanhfast(zg);
    float hh = sigf(zo)*tanhfast(cc);
    cOwn = cc;
    ast64(HC + 128 + (u0+tid), (unsigned long long)pk2(hh,cc) | (1ull<<32));
  }

  for (int t=0; t<TLEN; ++t){
    const unsigned sq = (unsigned)(t+1);
    unsigned long long* slot = REC + (size_t)(t&1)*GW*RECU;
    unsigned long long* hcg  = HC + (size_t)((t+1)&1)*128;
    unsigned long long* hcp  = HC + (size_t)(t&1)*128;
    unsigned long long* fr   = FLG + (size_t)(t&1)*GW*16;          // slots 0..63
    unsigned long long* fh   = FLG + (size_t)(64 + (t&1)*GW)*16;   // slots 64..127

    // PH1: 100 lanes each poll+decode one seq-embedded hc word (single IC trip)
    if (tid < 100){
      const unsigned long long* p0 = hcg + tid;
      unsigned long long v;
      for(;;){ v=ald64(p0); if((unsigned)(v>>32)==sq) break; __builtin_amdgcn_s_sleep(1); }
      unsigned lo=(unsigned)v;
      hL[tid]=blo(lo); cL[tid]=bhi(lo);
    }
    __syncthreads();                                      // B1
    // PH2: tsa[k] = state · tag_attn_w2[k]
    if (tid<400){
      int k=tid>>2, q=tid&3, off=q*50;
      const float* sb = (off<100)? (hL+off) : (cL+(off-100));
      float acc=0.f;
      #pragma unroll
      for (int i=0;i<25;i++){ unsigned u=tw2L[k*101+q*25+i]; acc += sb[2*i]*blo(u) + sb[2*i+1]*bhi(u); }
      acc += __shfl_xor(acc,1,4); acc += __shfl_xor(acc,2,4);
      if (q==0) tsaL[k]=acc;
    }
    __syncthreads();                                      // B2
    { // PH3: tag scores (8 thr/tag)
      int sp=tid>>3, l8=tid&7;
      float acc=0.f;
      for (int k=l8;k<100;k+=8){
        unsigned u=tw1L[sp*51+(k>>1)];
        float w1v=(k&1)? bhi(u) : blo(u);
        acc += tanhfast(w1v + tsaL[k]) * tavL[k];
      }
      acc += __shfl_xor(acc,1,8); acc += __shfl_xor(acc,2,8); acc += __shfl_xor(acc,4,8);
      if (l8==0) uL[sp]=acc;
    }
    __syncthreads();                                      // B3
    if (tid<64){ // PH4: softmax over 64 tags
      float v=uL[tid], m=v;
      for (int d=1;d<64;d<<=1) m=fmaxf(m,__shfl_xor(m,d,64));
      float e=__expf(v-m), ssum=e;
      for (int d=1;d<64;d<<=1) ssum+=__shfl_xor(ssum,d,64);
      tawL[tid]=e*rcpf(ssum);
    }
    __syncthreads();                                      // B4
    if (tid<400){ // PH5: tag_ctx (4 thr/hh) + fold ns
      int hh=tid>>2, q=tid&3;
      float acc=0.f;
      #pragma unroll
      for (int i=0;i<16;i++){
        int s=q*16+i;
        unsigned u=tagvL[s*51+(hh>>1)];
        acc += tawL[s]*((hh&1)? bhi(u):blo(u));
      }
      acc += __shfl_xor(acc,1,4); acc += __shfl_xor(acc,2,4);
      if (q==0){ tcL[hh]=acc; nsL[hh]=hL[hh]+acc; nsL[100+hh]=cL[hh]+acc; }
    }
    __syncthreads();                                      // B5
    if (tid<400){ // PH6: a23[k]
      int k=tid>>2, q=tid&3, off=q*50;
      float acc=0.f;
      #pragma unroll
      for (int i=0;i<25;i++){ unsigned u=aw2L[k*101+q*25+i]; acc += nsL[off+2*i]*blo(u) + nsL[off+2*i+1]*bhi(u); }
      acc += __shfl_xor(acc,1,4); acc += __shfl_xor(acc,2,4);
      if (q==0){
        float a3=0.f;
        #pragma unroll
        for (int i=0;i<5;i++) a3 += prevL[i]*aw3L[k*5+i];
        a23L[k]=acc+a3;
      }
    }
    __syncthreads();                                      // B6
    { // PH7: own 64 rows' scores (8 lanes/row)
      int r=tid>>3, l8=tid&7;
      float acc=0.f;
      for (int k=l8;k<100;k+=8){
        unsigned u=w1L[r*51+(k>>1)];
        float w1v=(k&1)? bhi(u) : blo(u);
        acc += tanhfast(w1v + a23L[k]) * avL[k];
      }
      acc += __shfl_xor(acc,1,8); acc += __shfl_xor(acc,2,8); acc += __shfl_xor(acc,4,8);
      if (l8==0) srowL[r]=acc;
    }
    __syncthreads();                                      // B7
    if (tid<64){ // PH8: local stats + argmax over own 64 rows
      float v=srowL[tid], m=v;
      for (int d=1;d<64;d<<=1) m=fmaxf(m,__shfl_xor(m,d,64));
      float e=__expf(v-m); eRL[tid]=e;
      float Ss=e;
      for (int d=1;d<64;d<<=1) Ss+=__shfl_xor(Ss,d,64);
      float bv=v; int bi=w*CHK+tid;
      for (int d=1;d<64;d<<=1){
        float ov=__shfl_xor(bv,d,64); int oi=__shfl_xor(bi,d,64);
        if (ov>bv || (ov==bv && oi<bi)){ bv=ov; bi=oi; }
      }
      if (tid==0){ hdrL[0]=m; hdrL[1]=Ss; hdrL[2]=bv; ((int*)hdrL)[3]=bi; }
    }
    __syncthreads();                                      // B8
    // PH9 (tid<400): ctx partial. Wave 7 concurrently publishes scores+hdr + flag fh.
    if (tid<400){
      int d=tid>>1, hf=tid&1;
      float acc=0.f;
      #pragma unroll 8
      for (int i=0;i<32;i++){
        int rr=hf*32+i;
        unsigned u=encL[rr*101+(d>>1)];
        acc += eRL[rr]*((d&1)? bhi(u):blo(u));
      }
      acc += __shfl_xor(acc,1,2);
      if (hf==0) ctxpL[d]=acc;
    } else if (tid>=448){
      int lane = tid-448;
      unsigned long long* rp = slot + (size_t)w*RECU;
      if (lane < 16){ int j=lane;
        ast64(rp+50+j, (unsigned long long)pk2(srowL[4*j],srowL[4*j+1])
                     | ((unsigned long long)pk2(srowL[4*j+2],srowL[4*j+3])<<32));
      } else if (lane==16)
        ast64(rp+66, (unsigned long long)__float_as_uint(hdrL[0])
                   | ((unsigned long long)__float_as_uint(hdrL[1])<<32));
      else if (lane==17)
        ast64(rp+67, (unsigned long long)__float_as_uint(hdrL[2])
                   | ((unsigned long long)(unsigned)((int*)hdrL)[3]<<32));
      vm0();
      if (lane==0) ast64(fh + (size_t)w*16, (unsigned long long)sq);
    }
    __syncthreads();                                      // B9

    // PH10/11: wave 7 publishes ctxp + flag fr, then its zpre; tid<448 do zpre.
    #define ZPRE_ROW() do{ \
      if (jslot < nact){ \
        float acc=0.f; \
        { unsigned u=wha0; acc += hL[2*l]*blo(u) + hL[2*l+1]*bhi(u); } \
        if (l<18){ unsigned u=wha1; acc += hL[2*(32+l)]*blo(u) + hL[2*(32+l)+1]*bhi(u); } \
        { unsigned u=wta0; acc += tcL[2*l]*blo(u) + tcL[2*l+1]*bhi(u); } \
        if (l<18){ unsigned u=wta1; acc += tcL[2*(32+l)]*blo(u) + tcL[2*(32+l)+1]*bhi(u); } \
        acc += __shfl_xor(acc,1,32); acc += __shfl_xor(acc,2,32); \
        acc += __shfl_xor(acc,4,32); acc += __shfl_xor(acc,8,32); acc += __shfl_xor(acc,16,32); \
        if (l==0) zOwnL[jslot] = acc + ws[OFF_PEW + t*400 + row]; \
      } \
    }while(0)

    if (tid < 448){
      ZPRE_ROW();
    } else {
      int lane = tid-448;
      unsigned long long* rp = slot + (size_t)w*RECU;
      if (lane < 50)
        ast64(rp+lane, (unsigned long long)pk2(ctxpL[4*lane],ctxpL[4*lane+1])
                     | ((unsigned long long)pk2(ctxpL[4*lane+2],ctxpL[4*lane+3])<<32));
      vm0();
      if (lane==0) ast64(fr + (size_t)w*16, (unsigned long long)sq);
      ZPRE_ROW();   // jslot 14,15 (active only for blocks 0-3)
    }

    // PH12a: wave 0 polls hdr flags (fh)
    if (tid < 64){
      int ok = (tid >= GW) ? 1 : 0;
      for(;;){
        if (!ok) ok = ((unsigned)ald64(fh + (size_t)tid*16) == sq);
        if (__all(ok)) break;
      }
    }
    __syncthreads();                                      // B10
    // PH12b: wave 0 polls ctxp flags (fr); wave 7 reads hdrs + in-wave reduce
    if (tid < 64){
      int ok = (tid >= GW) ? 1 : 0;
      for(;;){
        if (!ok) ok = ((unsigned)ald64(fr + (size_t)tid*16) == sq);
        if (__all(ok)) break;
      }
    } else if (tid>=448){
      int lane=tid-448, r=lane&31, up=lane>>5;
      unsigned long long v = ald64(slot + (size_t)r*RECU + 66 + up);
      float x0 = __uint_as_float((unsigned)v);
      float x1 = __uint_as_float((unsigned)(v>>32));
      int   xi = (int)(unsigned)(v>>32);
      float pv = x0; int pi = xi;
      #pragma unroll
      for (int d=1;d<32;d<<=1){
        float ov=__shfl_xor(pv,d,32); int oi=__shfl_xor(pi,d,32);
        if (up){ if (ov>pv || (ov==pv && oi<pi)){ pv=ov; pi=oi; } }
        else   { pv = fmaxf(pv,ov); }
      }
      if (!up){
        float sc = __expf(x0 - pv);                       // pv = M
        sclL[r] = sc;
        float ss = sc * x1;
        #pragma unroll
        for (int d=1;d<32;d<<=1) ss += __shfl_xor(ss,d,32);
        if (r==0){ MS[0]=pv; MS[1]=ss; }
      } else {
        if (r==0) amiL = pi;
      }
    }
    __syncthreads();                                      // B11
    // PH13: merged ctx bulk-read + scl-weighted assemble (scl/MS already ready)
    if (tid<400){
      float rS = rcpf(MS[1]);
      int dw=tid>>3, s8=tid&7;
      float c0=0.f,c1=0.f,c2=0.f,c3=0.f;
      #pragma unroll
      for (int i=0;i<4;i++){
        unsigned long long p = ald64(slot + (size_t)(s8*4+i)*RECU + dw);
        float sc = sclL[s8*4+i];
        unsigned lo=(unsigned)p, hi=(unsigned)(p>>32);
        c0 += blo(lo)*sc; c1 += bhi(lo)*sc;
        c2 += blo(hi)*sc; c3 += bhi(hi)*sc;
      }
      #pragma unroll
      for (int d=1;d<8;d<<=1){
        c0 += __shfl_xor(c0,d,8); c1 += __shfl_xor(c1,d,8);
        c2 += __shfl_xor(c2,d,8); c3 += __shfl_xor(c3,d,8);
      }
      if (s8==0){
        ctxL[4*dw+0]=c0*rS; ctxL[4*dw+1]=c1*rS;
        ctxL[4*dw+2]=c2*rS; ctxL[4*dw+3]=c3*rS;
      }
    }
    __syncthreads();                                      // B12
    // PH16: own-row z += ctx·Wihc
    if (jslot < nact){
      float acc=0.f;
      { unsigned u=wca0; acc += ctxL[2*l]*blo(u) + ctxL[2*l+1]*bhi(u); }
      { unsigned u=wca1; acc += ctxL[2*(32+l)]*blo(u) + ctxL[2*(32+l)+1]*bhi(u); }
      { unsigned u=wca2; acc += ctxL[2*(64+l)]*blo(u) + ctxL[2*(64+l)+1]*bhi(u); }
      if (l<4){ unsigned u=wca3; acc += ctxL[2*(96+l)]*blo(u) + ctxL[2*(96+l)+1]*bhi(u); }
      acc += __shfl_xor(acc,1,32); acc += __shfl_xor(acc,2,32);
      acc += __shfl_xor(acc,4,32); acc += __shfl_xor(acc,8,32); acc += __shfl_xor(acc,16,32);
      if (l==0) zOwnL[jslot] += acc;
    }
    __syncthreads();                                      // B13
    // PH15a: next-step prev window (5 system loads; overlaps PH17 + hc hop).
    if (tid>=440 && tid<445){
      int i=tid-440;
      int st = amiL-1; st = st<0?0:st; st = st>NN-6?NN-6:st;
      int g = st+i, r=g>>6, lr=g&63;
      unsigned long long v = ald64(slot + (size_t)r*RECU + 50 + (lr>>2));
      unsigned half = (lr&2)? (unsigned)(v>>32) : (unsigned)v;
      float sc = (lr&1)? bhi(half) : blo(half);
      prevL[i] = __expf(sc - MS[0]) * rcpf(MS[1]);
    }
    // PH17: own-unit gates (f32 own cell state); single seq-embedded hc store
    if (tid < nu){
      float zi=zOwnL[tid*4+0], zf=zOwnL[tid*4+1], zg=zOwnL[tid*4+2], zo=zOwnL[tid*4+3];
      float cc = sigf(zf)*cOwn + sigf(zi)*tanhfast(zg);
      float hh = sigf(zo)*tanhfast(cc);
      cOwn = cc;
      ast64(hcp + (u0+tid), (unsigned long long)pk2(hh,cc)
                          | ((unsigned long long)(sq+1)<<32));
      ws[OFF_HOUT + t*100 + (u0+tid)] = hh;
    }
    // next iteration's PH1 poll + B1 is the inter-step sync
  }
}

// ---------------- kLoss: parallel logits + log-softmax over V ----------------
__global__ __launch_bounds__(256) void kLoss(const float* outW, const float* outb,
                                             const int* oid, float* ws)
{
  const int b=blockIdx.x, tid=threadIdx.x;
  const int tile=b>>1, hf=b&1, t0=tile*16;
  __shared__ float s_hn[16*100];
  __shared__ int   s_oid[16];
  __shared__ float red[4][16][3];
  for (int i=tid;i<1600;i+=256) s_hn[i]=ws[OFF_HOUT + t0*100 + i];
  if (tid<16) s_oid[tid]=oid[t0+tid];
  __syncthreads();
  const int VSPLIT = 25129;
  int vbeg = hf? VSPLIT : 0;
  int vend = hf? VOC : VSPLIT;
  float rm[16], rs[16], ol[16];
  #pragma unroll
  for (int tt=0;tt<16;tt++){ rm[tt]=-1e30f; rs[tt]=0.f; ol[tt]=-1e30f; }
  for (int v=vbeg+tid; v<vend; v+=256){
    const float4* wr = (const float4*)(outW + (size_t)v*100);
    float acc[16];
    #pragma unroll
    for (int tt=0;tt<16;tt++) acc[tt]=0.f;
    #pragma unroll 5
    for (int q=0;q<25;q++){
      float4 wv = wr[q];
      #pragma unroll
      for (int tt=0;tt<16;tt++){
        float4 hv = *(const float4*)(s_hn + tt*100 + q*4);
        acc[tt] += wv.x*hv.x + wv.y*hv.y + wv.z*hv.z + wv.w*hv.w;
      }
    }
    float bb = outb[v];
    #pragma unroll
    for (int tt=0;tt<16;tt++){
      float lg = acc[tt] + bb;
      if (v == s_oid[tt]) ol[tt] = fmaxf(ol[tt], lg);
      if (lg <= rm[tt]) rs[tt] += __expf(lg - rm[tt]);
      else { rs[tt] = rs[tt]*__expf(rm[tt]-lg) + 1.0f; rm[tt]=lg; }
    }
  }
  int wv2=tid>>6, ln=tid&63;
  #pragma unroll
  for (int tt=0;tt<16;tt++){
    float m=rm[tt], sv=rs[tt], o=ol[tt];
    for (int d=1;d<64;d<<=1){
      float om=__shfl_xor(m,d,64), os=__shfl_xor(sv,d,64), oo=__shfl_xor(o,d,64);
      float M2=fmaxf(m,om);
      sv = sv*__expf(m-M2) + os*__expf(om-M2);
      m=M2; o=fmaxf(o,oo);
    }
    if (ln==0){ red[wv2][tt][0]=m; red[wv2][tt][1]=sv; red[wv2][tt][2]=o; }
  }
  __syncthreads();
  if (tid<16){
    float M=-1e30f;
    for (int q=0;q<4;q++) M=fmaxf(M,red[q][tid][0]);
    float S=0.f, O=-1e30f;
    for (int q=0;q<4;q++){ S += red[q][tid][1]*__expf(red[q][tid][0]-M); O=fmaxf(O,red[q][tid][2]); }
    float* pb = ws + OFF_PB + (((tile*2)+hf)*16 + tid)*4;
    pb[0]=M; pb[1]=S; pb[2]=O;
  }
}

// ---------------- kFinal: combine halves, sum, scale ----------------
__global__ void kFinal(const float* weight, float* ws, float* out){
  __shared__ float red[256];
  int tid=threadIdx.x;
  float acc=0.f;
  for (int t=tid;t<TLEN;t+=256){
    int tile=t>>4, tt=t&15;
    const float* p0 = ws + OFF_PB + ((tile*2+0)*16+tt)*4;
    const float* p1 = ws + OFF_PB + ((tile*2+1)*16+tt)*4;
    float M=fmaxf(p0[0],p1[0]);
    float S=p0[1]*__expf(p0[0]-M) + p1[1]*__expf(p1[0]-M);
    float O=fmaxf(p0[2],p1[2]);
    acc += (M + logf(S)) - O;
  }
  red[tid]=acc; __syncthreads();
  for (int d=128; d>0; d>>=1){
    if (tid<d) red[tid]+=red[tid+d];
    __syncthreads();
  }
  if (tid==0) out[0]=red[0]*weight[0];
}

// ---------------- launch ----------------
extern "C" void kernel_launch(void* const* d_in, const int* in_sizes, int n_in,
                              void* d_out, int out_size, void* d_ws, size_t ws_size,
                              hipStream_t stream) {
  const int*   src      = (const int*)  d_in[0];
  const int*   tag      = (const int*)  d_in[1];
  const int*   oid      = (const int*)  d_in[2];
  const float* weight   = (const float*)d_in[3];
  const float* emb_char = (const float*)d_in[4];
  const float* emb_tag  = (const float*)d_in[5];
  const float* fWih=(const float*)d_in[6],  *fWhh=(const float*)d_in[7],  *fb=(const float*)d_in[8];
  const float* bWih=(const float*)d_in[9],  *bWhh=(const float*)d_in[10], *bb=(const float*)d_in[11];
  const float* tWih=(const float*)d_in[12], *tWhh=(const float*)d_in[13], *tb=(const float*)d_in[14];
  const float* dWih=(const float*)d_in[15], *dWhh=(const float*)d_in[16], *db=(const float*)d_in[17];
  const float* aw1 =(const float*)d_in[18], *aw2=(const float*)d_in[19];
  const float* aw3 =(const float*)d_in[20], *av =(const float*)d_in[21];
  const float* taw1=(const float*)d_in[22], *taw2=(const float*)d_in[23], *tavv=(const float*)d_in[24];
  const float* outW=(const float*)d_in[25], *outb=(const float*)d_in[26];
  float* ws  = (float*)d_ws;
  float* out = (float*)d_out;

  kInit<<<8, 256, 0, stream>>>(ws);
  kPrep<<<2*NN+TTAG+TLEN, 512, 0, stream>>>(src,tag,oid,emb_char,emb_tag,
                                            fWih,fb,bWih,bb,tWih,tb,dWih,db,ws);
  kEnc<<<3,512,0,stream>>>(fWhh,bWhh,tWhh,taw1,dWih,ws);
  kMid<<<NN,128,0,stream>>>(aw1,ws);
  kDec<<<GW,512,0,stream>>>(dWhh,dWih,aw2,aw3,av,taw2,tavv,ws);
  kLoss<<<256,256,0,stream>>>(outW,outb,oid,ws);
  kFinal<<<1,256,0,stream>>>(weight,ws,out);
}

// Round 13
// 24713.974 us; speedup vs baseline: 1.2307x; 1.0486x over previous
//
#include <hip/hip_runtime.h>
#include <math.h>

// ---------------- problem sizes ----------------
#define NN   2048   // source length
#define TLEN 2048   // target length
#define TTAG 64     // tags
#define VOC  50257
#define GW   32     // decoder blocks; each owns CHK source rows + 3-4 hidden units
#define CHK  64     // source rows per block
#define RECU 80     // u64 stride per record (68 used)
static_assert(GW * CHK == NN, "chunking");

// ---------------- workspace layout (float units) ----------------
#define OFF_XF    0                          // NN*400
#define OFF_XB    (OFF_XF  + NN*400)         // NN*400
#define OFF_TGX   (OFF_XB  + NN*400)         // TTAG*400
#define OFF_PEW   (OFF_TGX + TTAG*400)       // TLEN*400
#define OFF_ENC   (OFF_PEW + TLEN*400)       // NN*200
#define OFF_W1DT  (OFF_ENC + NN*200)         // NN*100
#define OFF_TAGV  (OFF_W1DT+ NN*100)         // TTAG*100
#define OFF_TGW1  (OFF_TAGV+ TTAG*100)       // TTAG*100
#define OFF_TGW   (OFF_TGW1+ TTAG*100)       // TTAG*400
#define OFF_HOUT  (OFF_TGW + TTAG*400)       // TLEN*100
#define OFF_REC   (OFF_HOUT+ TLEN*100)       // 2*GW*RECU u64
#define OFF_HC    (OFF_REC + 2*GW*RECU*2)    // 2*128 u64 (seq-embedded h/c words)
#define OFF_FLG   (OFF_HC  + 2*128*2)        // 2048 u64 flags (128B-spread)
#define OFF_PB    (OFF_FLG + 4096)           // loss partials

// record u64 words: [0..49] ctxp 4xbf16/word, [50..65] scores 4xbf16/word (64 rows),
//   [66]={S_w f32 | amax f32}, [67]={amax f32 | idx}
// NO-MAX softmax: scores bounded by sum|av| (tanh in [-1,1]) so exp(s) is safe;
// per-block stat is a plain sum, global softmax = sum of sums. No rescale path.
// SPLIT publish: words 50..67 + flag fh concurrent with PH9; words 0..49 + fr at PH10.
// hc buffer b: word u = { h bf16 | c bf16 | seq u32 }  (single-trip, seq-embedded)

// ---------------- helpers ----------------
__device__ __forceinline__ float rcpf(float x){ return __builtin_amdgcn_rcpf(x); }
__device__ __forceinline__ float sigf(float x){ return rcpf(1.0f+__expf(-x)); }
__device__ __forceinline__ float tanhfast(float x){
  float e = __expf(2.0f*x);
  return 1.0f - 2.0f*rcpf(e+1.0f);
}
__device__ __forceinline__ unsigned short f2b(float x){
  unsigned b=__float_as_uint(x);
  return (unsigned short)((b + 0x7fffu + ((b>>16)&1u))>>16);
}
__device__ __forceinline__ unsigned pk2(float a,float b){ return (unsigned)f2b(a) | ((unsigned)f2b(b)<<16); }
__device__ __forceinline__ float blo(unsigned u){ return __uint_as_float(u<<16); }
__device__ __forceinline__ float bhi(unsigned u){ return __uint_as_float(u&0xffff0000u); }

__device__ __forceinline__ unsigned long long ald64(const unsigned long long* p){
  return __hip_atomic_load(p,__ATOMIC_RELAXED,__HIP_MEMORY_SCOPE_SYSTEM);
}
__device__ __forceinline__ void ast64(unsigned long long* p, unsigned long long v){
  __hip_atomic_store(p,v,__ATOMIC_RELAXED,__HIP_MEMORY_SCOPE_SYSTEM);
}
__device__ __forceinline__ void vm0(){ asm volatile("s_waitcnt vmcnt(0)" ::: "memory"); }

// ---------------- kInit: zero flag region (every launch / replay) ----------------
__global__ void kInit(float* ws){
  unsigned long long* f = (unsigned long long*)(ws + OFF_FLG);
  int i = blockIdx.x*256 + threadIdx.x;
  if (i < 2048) ast64(f+i, 0ull);
}

// ---------------- kPrep: all input-side GEMVs (parallel) ----------------
__global__ __launch_bounds__(512) void kPrep(
    const int* src, const int* tag, const int* oid,
    const float* emb_char, const float* emb_tag,
    const float* fWih, const float* fb,
    const float* bWih, const float* bb,
    const float* tWih, const float* tb,
    const float* dWih, const float* db, float* ws)
{
  int r = blockIdx.x, j = threadIdx.x;
  if (j >= 400) return;
  if (r < NN) {
    const float* e = emb_char + (size_t)src[r]*32;
    const float* Wr = fWih + j*32;
    float a = fb[j];
    #pragma unroll
    for (int q=0;q<32;q++) a += e[q]*Wr[q];
    ws[OFF_XF + r*400 + j] = a;
  } else if (r < 2*NN) {
    int n = r - NN;
    const float* e = emb_char + (size_t)src[n]*32;
    const float* Wr = bWih + j*32;
    float a = bb[j];
    #pragma unroll
    for (int q=0;q<32;q++) a += e[q]*Wr[q];
    ws[OFF_XB + n*400 + j] = a;
  } else if (r < 2*NN + TTAG) {
    int s = r - 2*NN;
    const float* e = emb_tag + (size_t)tag[s]*32;
    const float* Wr = tWih + j*32;
    float a = tb[j];
    #pragma unroll
    for (int q=0;q<32;q++) a += e[q]*Wr[q];
    ws[OFF_TGX + s*400 + j] = a;
  } else {
    int t = r - (2*NN + TTAG);
    int pid = (t==0) ? 0 : oid[t-1];
    const float* e = emb_char + (size_t)pid*32;
    const float* Wr = dWih + (size_t)j*332 + 300;
    float a = db[j];
    #pragma unroll
    for (int q=0;q<32;q++) a += e[q]*Wr[q];
    ws[OFF_PEW + t*400 + j] = a;
  }
}

// ---------------- kEnc: sequential LSTM scans (3 independent blocks) ----------------
// z-loops FULLY unrolled so whh[100] stays in VGPRs.
struct EncShared {
  float tvs[TTAG*100];
  float sa [TTAG*64];
  float hbuf[100];
  float zbuf[400];
};

__device__ void lstm_block(const float* Whh, const float* xbase, float* ws,
                           int reverse, int col, EncShared* sh)
{
  int tid = threadIdx.x;
  float whh[100];
  if (tid < 400){
    #pragma unroll
    for (int k=0;k<100;k++) whh[k] = Whh[tid*100+k];
  }
  float c = 0.f;
  if (tid < 100) sh->hbuf[tid] = 0.f;
  __syncthreads();
  for (int i=0;i<NN;i++){
    int n = reverse ? (NN-1-i) : i;
    if (tid < 400){
      float z = xbase[n*400+tid];
      #pragma unroll
      for (int k=0;k<100;k++) z += whh[k]*sh->hbuf[k];
      sh->zbuf[tid] = z;
    }
    __syncthreads();
    if (tid < 100){
      float zi=sh->zbuf[tid], zf=sh->zbuf[tid+100], zg=sh->zbuf[tid+200], zo=sh->zbuf[tid+300];
      c = sigf(zf)*c + sigf(zi)*tanhfast(zg);
      float h = sigf(zo)*tanhfast(c);
      sh->hbuf[tid] = h;
      ws[OFF_ENC + n*200 + col + tid] = h;
    }
    __syncthreads();
  }
}

__global__ __launch_bounds__(512,1) void kEnc(
    const float* fWhh, const float* bWhh, const float* tWhh,
    const float* taw1, const float* dWih, float* ws)
{
  __shared__ EncShared sh;
  int b = blockIdx.x, tid = threadIdx.x;
  if (b == 0){ lstm_block(fWhh, ws+OFF_XF, ws, 0, 0,   &sh); return; }
  if (b == 1){ lstm_block(bWhh, ws+OFF_XB, ws, 1, 100, &sh); return; }

  // ---- block 2: tag LSTM + self-attn + tagv-derived tables ----
  {
    float whh[100];
    if (tid<400){
      #pragma unroll
      for (int k=0;k<100;k++) whh[k] = tWhh[tid*100+k];
    }
    float c = 0.f;
    if (tid<100) sh.hbuf[tid] = 0.f;
    __syncthreads();
    for (int s=0;s<TTAG;s++){
      if (tid<400){
        float z = ws[OFF_TGX + s*400 + tid];
        #pragma unroll
        for (int k=0;k<100;k++) z += whh[k]*sh.hbuf[k];
        sh.zbuf[tid] = z;
      }
      __syncthreads();
      if (tid<100){
        float zi=sh.zbuf[tid], zf=sh.zbuf[tid+100], zg=sh.zbuf[tid+200], zo=sh.zbuf[tid+300];
        c = sigf(zf)*c + sigf(zi)*tanhfast(zg);
        float h = sigf(zo)*tanhfast(c);
        sh.hbuf[tid] = h;
        sh.tvs[s*100+tid] = h;
      }
      __syncthreads();
    }
  }
  for (int idx=tid; idx<TTAG*TTAG; idx+=512){
    int s=idx>>6, t2=idx&63;
    float a=0.f;
    #pragma unroll 10
    for (int h=0;h<100;h++) a += sh.tvs[s*100+h]*sh.tvs[t2*100+h];
    sh.sa[idx]=a;
  }
  __syncthreads();
  if (tid<TTAG){
    float m=-1e30f;
    for (int t2=0;t2<64;t2++) m = fmaxf(m, sh.sa[tid*64+t2]);
    float sum=0.f;
    for (int t2=0;t2<64;t2++){ float e=__expf(sh.sa[tid*64+t2]-m); sh.sa[tid*64+t2]=e; sum+=e; }
    float r=1.f/sum;
    for (int t2=0;t2<64;t2++) sh.sa[tid*64+t2]*=r;
  }
  __syncthreads();
  float tvloc[13]; int cnt=0;
  for (int idx=tid; idx<TTAG*100; idx+=512){
    int t2=idx/100, hh=idx%100;
    float a = sh.tvs[t2*100+hh];
    for (int s=0;s<64;s++) a += sh.tvs[s*100+hh]*sh.sa[s*64+t2];
    tvloc[cnt++]=a;
    ws[OFF_TAGV+idx]=a;
  }
  __syncthreads();
  float* tagvs = sh.sa;
  cnt=0;
  for (int idx=tid; idx<TTAG*100; idx+=512) tagvs[idx]=tvloc[cnt++];
  __syncthreads();
  for (int idx=tid; idx<TTAG*100; idx+=512){
    int s=idx/100, k=idx%100;
    float a=0.f;
    #pragma unroll 10
    for (int h=0;h<100;h++) a += tagvs[s*100+h]*taw1[k*100+h];
    ws[OFF_TGW1+idx]=a;
  }
  for (int idx=tid; idx<TTAG*400; idx+=512){
    int s=idx/400, j=idx%400;
    const float* Wr = dWih + (size_t)j*332 + 200;
    float a=0.f;
    #pragma unroll 10
    for (int h=0;h<100;h++) a += tagvs[s*100+h]*Wr[h];
    ws[OFF_TGW+idx]=a;
  }
}

// ---------------- kMid: w1dt = enc @ attn_w1.T ----------------
__global__ void kMid(const float* aw1, float* ws){
  __shared__ float er[200];
  int n=blockIdx.x, tid=threadIdx.x;
  for (int i=tid;i<200;i+=128) er[i]=ws[OFF_ENC+n*200+i];
  __syncthreads();
  if (tid<100){
    const float* Wr = aw1 + tid*200;
    float a=0.f;
    #pragma unroll 8
    for (int d=0;d<200;d++) a += er[d]*Wr[d];
    ws[OFF_W1DT + n*100 + tid]=a;
  }
}

// ---------------- kDec: 512-thread decoder; no-max softmax; 11-barrier chain ----------------
__global__ __launch_bounds__(512) void kDec(
    const float* dWhh, const float* dWih,
    const float* aw2, const float* aw3, const float* av,
    const float* taw2, const float* tav, float* ws)
{
  // padded strides: 101 per 100-wide row, 51 per 50-wide row (bank-conflict fix)
  __shared__ unsigned aw2L[100*101];
  __shared__ unsigned tw2L[100*101];
  __shared__ unsigned tw1L[TTAG*51];
  __shared__ unsigned tagvL[TTAG*51];
  __shared__ unsigned w1L[CHK*51];
  __shared__ unsigned encL[CHK*101];
  __shared__ float tavL[100], avL[100], aw3L[500];
  __shared__ float hL[100], cL[100], tcL[100], tsaL[100], nsL[200];
  __shared__ float uL[TTAG], tawL[TTAG];
  __shared__ float ctxL[200], a23L[100], ctxpL[200];
  __shared__ float srowL[CHK], eRL[CHK];
  __shared__ float zOwnL[16];
  __shared__ float prevL[5];
  __shared__ float Sg;       // global softmax denominator
  __shared__ int   amiL;

  const int tid = threadIdx.x;
  const int w   = blockIdx.x;
  unsigned long long* REC = (unsigned long long*)(ws + OFF_REC);
  unsigned long long* HC  = (unsigned long long*)(ws + OFF_HC);
  unsigned long long* FLG = (unsigned long long*)(ws + OFF_FLG);

  // ---- hidden-unit ownership: blocks 0..3 -> 4 units, 4..31 -> 3 units ----
  const int nu = (w<4)? 4 : 3;
  const int u0 = (w<4)? w*4 : 16 + (w-4)*3;
  const int nact = nu*4;
  const int jslot = tid>>5, l = tid&31;

  // ---- tiny per-thread weight registers (own gate-rows only) ----
  unsigned wca0=0,wca1=0,wca2=0,wca3=0, wha0=0,wha1=0, wta0=0,wta1=0;
  int row=0;
  if (jslot < nact){
    row = (jslot&3)*100 + u0 + (jslot>>2);
    const float* Wr = dWih + (size_t)row*332;
    wca0=pk2(Wr[2*l],Wr[2*l+1]);
    wca1=pk2(Wr[2*(32+l)],Wr[2*(32+l)+1]);
    wca2=pk2(Wr[2*(64+l)],Wr[2*(64+l)+1]);
    if (l<4) wca3=pk2(Wr[2*(96+l)],Wr[2*(96+l)+1]);
    const float* Wh = dWhh + (size_t)row*100;
    wha0=pk2(Wh[2*l],Wh[2*l+1]);
    if (l<18) wha1=pk2(Wh[2*(32+l)],Wh[2*(32+l)+1]);
    const float* Wt = Wr + 200;
    wta0=pk2(Wt[2*l],Wt[2*l+1]);
    if (l<18) wta1=pk2(Wt[2*(32+l)],Wt[2*(32+l)+1]);
  }
  // ---- LDS preload (padded strides) ----
  for (int i=tid;i<100*100;i+=512){ int k=i/100,p=i%100; aw2L[k*101+p]=pk2(aw2 [k*200+2*p], aw2 [k*200+2*p+1]); }
  for (int i=tid;i<100*100;i+=512){ int k=i/100,p=i%100; tw2L[k*101+p]=pk2(taw2[k*200+2*p], taw2[k*200+2*p+1]); }
  for (int i=tid;i<TTAG*50;i+=512){ int s=i/50,p=i%50; tw1L[s*51+p]=pk2(ws[OFF_TGW1+s*100+2*p], ws[OFF_TGW1+s*100+2*p+1]); }
  for (int i=tid;i<TTAG*50;i+=512){ int s=i/50,p=i%50; tagvL[s*51+p]=pk2(ws[OFF_TAGV+s*100+2*p], ws[OFF_TAGV+s*100+2*p+1]); }
  for (int i=tid;i<CHK*50;i+=512){ int r=i/50,p=i%50; w1L[r*51+p]=pk2(ws[OFF_W1DT+(w*CHK+r)*100+2*p], ws[OFF_W1DT+(w*CHK+r)*100+2*p+1]); }
  for (int i=tid;i<CHK*100;i+=512){ int r=i/100,p=i%100; encL[r*101+p]=pk2(ws[OFF_ENC+(w*CHK+r)*200+2*p], ws[OFF_ENC+(w*CHK+r)*200+2*p+1]); }
  if (tid<100){ tavL[tid]=tav[tid]; avL[tid]=av[tid]; }
  for (int i=tid;i<500;i+=512) aw3L[i]=aw3[i];
  if (tid<5)   prevL[tid]=0.f;
  if (tid<200) ctxL[tid]=ws[OFF_ENC + 2047*200 + tid];   // enc_last for init
  __syncthreads();

  // ---- init: own-row z0 -> h0,c0 -> publish hc (seq-embedded, single store) ----
  if (jslot < nact){
    float acc=0.f;
    { unsigned u=wca0; acc += ctxL[2*l]*blo(u) + ctxL[2*l+1]*bhi(u); }
    { unsigned u=wca1; acc += ctxL[2*(32+l)]*blo(u) + ctxL[2*(32+l)+1]*bhi(u); }
    { unsigned u=wca2; acc += ctxL[2*(64+l)]*blo(u) + ctxL[2*(64+l)+1]*bhi(u); }
    if (l<4){ unsigned u=wca3; acc += ctxL[2*(96+l)]*blo(u) + ctxL[2*(96+l)+1]*bhi(u); }
    acc += __shfl_xor(acc,1,32); acc += __shfl_xor(acc,2,32);
    acc += __shfl_xor(acc,4,32); acc += __shfl_xor(acc,8,32); acc += __shfl_xor(acc,16,32);
    if (l==0) zOwnL[jslot] = acc + ws[OFF_TGW + 63*400 + row] + ws[OFF_PEW + row];
  }
  __syncthreads();
  float cOwn = 0.f;   // own unit's cell state, f32, persists across steps (tid<nu)
  if (tid < nu){
    float zi=zOwnL[tid*4+0], zg=zOwnL[tid*4+2], zo=zOwnL[tid*4+3];
    float cc = sigf(zi)*tanhfast(zg);
    float hh = sigf(zo)*tanhfast(cc);
    cOwn = cc;
    ast64(HC + 128 + (u0+tid), (unsigned long long)pk2(hh,cc) | (1ull<<32));
  }

  for (int t=0; t<TLEN; ++t){
    const unsigned sq = (unsigned)(t+1);
    unsigned long long* slot = REC + (size_t)(t&1)*GW*RECU;
    unsigned long long* hcg  = HC + (size_t)((t+1)&1)*128;
    unsigned long long* hcp  = HC + (size_t)(t&1)*128;
    unsigned long long* fr   = FLG + (size_t)(t&1)*GW*16;          // slots 0..63
    unsigned long long* fh   = FLG + (size_t)(64 + (t&1)*GW)*16;   // slots 64..127

    // PH1: 100 lanes each poll+decode one seq-embedded hc word (single IC trip)
    if (tid < 100){
      const unsigned long long* p0 = hcg + tid;
      unsigned long long v;
      for(;;){ v=ald64(p0); if((unsigned)(v>>32)==sq) break; __builtin_amdgcn_s_sleep(1); }
      unsigned lo=(unsigned)v;
      hL[tid]=blo(lo); cL[tid]=bhi(lo);
    }
    __syncthreads();                                      // B1
    // PH2: tsa[k] = state · tag_attn_w2[k]
    if (tid<400){
      int k=tid>>2, q=tid&3, off=q*50;
      const float* sb = (off<100)? (hL+off) : (cL+(off-100));
      float acc=0.f;
      #pragma unroll
      for (int i=0;i<25;i++){ unsigned u=tw2L[k*101+q*25+i]; acc += sb[2*i]*blo(u) + sb[2*i+1]*bhi(u); }
      acc += __shfl_xor(acc,1,4); acc += __shfl_xor(acc,2,4);
      if (q==0) tsaL[k]=acc;
    }
    __syncthreads();                                      // B2
    { // PH3: tag scores (8 thr/tag)
      int sp=tid>>3, l8=tid&7;
      float acc=0.f;
      for (int k=l8;k<100;k+=8){
        unsigned u=tw1L[sp*51+(k>>1)];
        float w1v=(k&1)? bhi(u) : blo(u);
        acc += tanhfast(w1v + tsaL[k]) * tavL[k];
      }
      acc += __shfl_xor(acc,1,8); acc += __shfl_xor(acc,2,8); acc += __shfl_xor(acc,4,8);
      if (l8==0) uL[sp]=acc;
    }
    __syncthreads();                                      // B3
    if (tid<64){ // PH4: softmax over 64 tags
      float v=uL[tid], m=v;
      for (int d=1;d<64;d<<=1) m=fmaxf(m,__shfl_xor(m,d,64));
      float e=__expf(v-m), ssum=e;
      for (int d=1;d<64;d<<=1) ssum+=__shfl_xor(ssum,d,64);
      tawL[tid]=e*rcpf(ssum);
    }
    __syncthreads();                                      // B4
    if (tid<400){ // PH5: tag_ctx (4 thr/hh) + fold ns
      int hh=tid>>2, q=tid&3;
      float acc=0.f;
      #pragma unroll
      for (int i=0;i<16;i++){
        int s=q*16+i;
        unsigned u=tagvL[s*51+(hh>>1)];
        acc += tawL[s]*((hh&1)? bhi(u):blo(u));
      }
      acc += __shfl_xor(acc,1,4); acc += __shfl_xor(acc,2,4);
      if (q==0){ tcL[hh]=acc; nsL[hh]=hL[hh]+acc; nsL[100+hh]=cL[hh]+acc; }
    }
    __syncthreads();                                      // B5
    if (tid<400){ // PH6: a23[k]
      int k=tid>>2, q=tid&3, off=q*50;
      float acc=0.f;
      #pragma unroll
      for (int i=0;i<25;i++){ unsigned u=aw2L[k*101+q*25+i]; acc += nsL[off+2*i]*blo(u) + nsL[off+2*i+1]*bhi(u); }
      acc += __shfl_xor(acc,1,4); acc += __shfl_xor(acc,2,4);
      if (q==0){
        float a3=0.f;
        #pragma unroll
        for (int i=0;i<5;i++) a3 += prevL[i]*aw3L[k*5+i];
        a23L[k]=acc+a3;
      }
    }
    __syncthreads();                                      // B6
    { // PH7: own 64 rows' scores (8 lanes/row); eRL = exp(score) (no max shift)
      int r=tid>>3, l8=tid&7;
      float acc=0.f;
      for (int k=l8;k<100;k+=8){
        unsigned u=w1L[r*51+(k>>1)];
        float w1v=(k&1)? bhi(u) : blo(u);
        acc += tanhfast(w1v + a23L[k]) * avL[k];
      }
      acc += __shfl_xor(acc,1,8); acc += __shfl_xor(acc,2,8); acc += __shfl_xor(acc,4,8);
      if (l8==0){ srowL[r]=acc; eRL[r]=__expf(acc); }
    }
    __syncthreads();                                      // B7
    // PH9 (tid<400): ctx partials. Wave 7 concurrently: in-wave sum+argmax
    // over own 64 rows, publish scores + stats + flag fh.
    if (tid<400){
      int d=tid>>1, hf=tid&1;
      float acc=0.f;
      #pragma unroll 8
      for (int i=0;i<32;i++){
        int rr=hf*32+i;
        unsigned u=encL[rr*101+(d>>1)];
        acc += eRL[rr]*((d&1)? bhi(u):blo(u));
      }
      acc += __shfl_xor(acc,1,2);
      if (hf==0) ctxpL[d]=acc;
    } else if (tid>=448){
      int lane = tid-448;                 // 0..63
      float eS = eRL[lane];
      float sv = srowL[lane]; int si = w*CHK+lane;
      #pragma unroll
      for (int d=1;d<64;d<<=1){
        eS += __shfl_xor(eS,d,64);
        float ov=__shfl_xor(sv,d,64); int oi=__shfl_xor(si,d,64);
        if (ov>sv || (ov==sv && oi<si)){ sv=ov; si=oi; }
      }
      unsigned long long* rp = slot + (size_t)w*RECU;
      if (lane < 16){ int j=lane;
        ast64(rp+50+j, (unsigned long long)pk2(srowL[4*j],srowL[4*j+1])
                     | ((unsigned long long)pk2(srowL[4*j+2],srowL[4*j+3])<<32));
      } else if (lane==16)
        ast64(rp+66, (unsigned long long)__float_as_uint(eS)
                   | ((unsigned long long)__float_as_uint(sv)<<32));
      else if (lane==17)
        ast64(rp+67, (unsigned long long)__float_as_uint(sv)
                   | ((unsigned long long)(unsigned)si<<32));
      vm0();
      if (lane==0) ast64(fh + (size_t)w*16, (unsigned long long)sq);
    }
    __syncthreads();                                      // B9

    // PH10/11: wave 7 publishes ctxp + flag fr, does its zpre, then per-lane
    // fh-poll + hdr read + global S/argmax reduce. tid<448: zpre; wave 0 then
    // polls fr. Single barrier (B11) joins everything.
    #define ZPRE_ROW() do{ \
      if (jslot < nact){ \
        float acc=0.f; \
        { unsigned u=wha0; acc += hL[2*l]*blo(u) + hL[2*l+1]*bhi(u); } \
        if (l<18){ unsigned u=wha1; acc += hL[2*(32+l)]*blo(u) + hL[2*(32+l)+1]*bhi(u); } \
        { unsigned u=wta0; acc += tcL[2*l]*blo(u) + tcL[2*l+1]*bhi(u); } \
        if (l<18){ unsigned u=wta1; acc += tcL[2*(32+l)]*blo(u) + tcL[2*(32+l)+1]*bhi(u); } \
        acc += __shfl_xor(acc,1,32); acc += __shfl_xor(acc,2,32); \
        acc += __shfl_xor(acc,4,32); acc += __shfl_xor(acc,8,32); acc += __shfl_xor(acc,16,32); \
        if (l==0) zOwnL[jslot] = acc + ws[OFF_PEW + t*400 + row]; \
      } \
    }while(0)

    if (tid < 448){
      ZPRE_ROW();
      if (tid < 64){  // wave 0: poll all ctxp flags
        int ok = (tid >= GW) ? 1 : 0;
        for(;;){
          if (!ok) ok = ((unsigned)ald64(fr + (size_t)tid*16) == sq);
          if (__all(ok)) break;
        }
      }
    } else {
      int lane = tid-448;
      unsigned long long* rp = slot + (size_t)w*RECU;
      if (lane < 50)
        ast64(rp+lane, (unsigned long long)pk2(ctxpL[4*lane],ctxpL[4*lane+1])
                     | ((unsigned long long)pk2(ctxpL[4*lane+2],ctxpL[4*lane+3])<<32));
      vm0();
      if (lane==0) ast64(fr + (size_t)w*16, (unsigned long long)sq);
      ZPRE_ROW();   // jslot 14,15 (active only for blocks 0-3)
      // per-lane fh poll + hdr read + in-wave global reduce
      {
        int r = lane&31, up = lane>>5;
        const unsigned long long* fp = fh + (size_t)r*16;
        for(;;){ if ((unsigned)ald64(fp)==sq) break; __builtin_amdgcn_s_sleep(1); }
        unsigned long long v = ald64(slot + (size_t)r*RECU + 66 + up);
        if (!up){
          float ss = __uint_as_float((unsigned)v);        // S_w
          #pragma unroll
          for (int d=1;d<32;d<<=1) ss += __shfl_xor(ss,d,32);
          if (r==0) Sg = ss;
        } else {
          float pv = __uint_as_float((unsigned)v);        // amax val
          int   pi = (int)(unsigned)(v>>32);              // amax idx
          #pragma unroll
          for (int d=1;d<32;d<<=1){
            float ov=__shfl_xor(pv,d,32); int oi=__shfl_xor(pi,d,32);
            if (ov>pv || (ov==pv && oi<pi)){ pv=ov; pi=oi; }
          }
          if (r==0) amiL = pi;
        }
      }
    }
    __syncthreads();                                      // B11
    // PH13: merged ctx bulk-read + plain-sum assemble, divide by global S
    if (tid<400){
      float rS = rcpf(Sg);
      int dw=tid>>3, s8=tid&7;
      float c0=0.f,c1=0.f,c2=0.f,c3=0.f;
      #pragma unroll
      for (int i=0;i<4;i++){
        unsigned long long p = ald64(slot + (size_t)(s8*4+i)*RECU + dw);
        unsigned lo=(unsigned)p, hi=(unsigned)(p>>32);
        c0 += blo(lo); c1 += bhi(lo);
        c2 += blo(hi); c3 += bhi(hi);
      }
      #pragma unroll
      for (int d=1;d<8;d<<=1){
        c0 += __shfl_xor(c0,d,8); c1 += __shfl_xor(c1,d,8);
        c2 += __shfl_xor(c2,d,8); c3 += __shfl_xor(c3,d,8);
      }
      if (s8==0){
        ctxL[4*dw+0]=c0*rS; ctxL[4*dw+1]=c1*rS;
        ctxL[4*dw+2]=c2*rS; ctxL[4*dw+3]=c3*rS;
      }
    }
    __syncthreads();                                      // B12
    // PH16: own-row z += ctx·Wihc
    if (jslot < nact){
      float acc=0.f;
      { unsigned u=wca0; acc += ctxL[2*l]*blo(u) + ctxL[2*l+1]*bhi(u); }
      { unsigned u=wca1; acc += ctxL[2*(32+l)]*blo(u) + ctxL[2*(32+l)+1]*bhi(u); }
      { unsigned u=wca2; acc += ctxL[2*(64+l)]*blo(u) + ctxL[2*(64+l)+1]*bhi(u); }
      if (l<4){ unsigned u=wca3; acc += ctxL[2*(96+l)]*blo(u) + ctxL[2*(96+l)+1]*bhi(u); }
      acc += __shfl_xor(acc,1,32); acc += __shfl_xor(acc,2,32);
      acc += __shfl_xor(acc,4,32); acc += __shfl_xor(acc,8,32); acc += __shfl_xor(acc,16,32);
      if (l==0) zOwnL[jslot] += acc;
    }
    __syncthreads();                                      // B13
    // PH15a: next-step prev window (5 system loads; overlaps PH17 + hc hop).
    if (tid>=440 && tid<445){
      int i=tid-440;
      int st = amiL-1; st = st<0?0:st; st = st>NN-6?NN-6:st;
      int g = st+i, r=g>>6, lr=g&63;
      unsigned long long v = ald64(slot + (size_t)r*RECU + 50 + (lr>>2));
      unsigned half = (lr&2)? (unsigned)(v>>32) : (unsigned)v;
      float sc = (lr&1)? bhi(half) : blo(half);
      prevL[i] = __expf(sc) * rcpf(Sg);
    }
    // PH17: own-unit gates (f32 own cell state); single seq-embedded hc store
    if (tid < nu){
      float zi=zOwnL[tid*4+0], zf=zOwnL[tid*4+1], zg=zOwnL[tid*4+2], zo=zOwnL[tid*4+3];
      float cc = sigf(zf)*cOwn + sigf(zi)*tanhfast(zg);
      float hh = sigf(zo)*tanhfast(cc);
      cOwn = cc;
      ast64(hcp + (u0+tid), (unsigned long long)pk2(hh,cc)
                          | ((unsigned long long)(sq+1)<<32));
      ws[OFF_HOUT + t*100 + (u0+tid)] = hh;
    }
    // next iteration's PH1 poll + B1 is the inter-step sync
  }
}

// ---------------- kLoss: parallel logits + log-softmax over V ----------------
__global__ __launch_bounds__(256) void kLoss(const float* outW, const float* outb,
                                             const int* oid, float* ws)
{
  const int b=blockIdx.x, tid=threadIdx.x;
  const int tile=b>>1, hf=b&1, t0=tile*16;
  __shared__ float s_hn[16*100];
  __shared__ int   s_oid[16];
  __shared__ float red[4][16][3];
  for (int i=tid;i<1600;i+=256) s_hn[i]=ws[OFF_HOUT + t0*100 + i];
  if (tid<16) s_oid[tid]=oid[t0+tid];
  __syncthreads();
  const int VSPLIT = 25129;
  int vbeg = hf? VSPLIT : 0;
  int vend = hf? VOC : VSPLIT;
  float rm[16], rs[16], ol[16];
  #pragma unroll
  for (int tt=0;tt<16;tt++){ rm[tt]=-1e30f; rs[tt]=0.f; ol[tt]=-1e30f; }
  for (int v=vbeg+tid; v<vend; v+=256){
    const float4* wr = (const float4*)(outW + (size_t)v*100);
    float acc[16];
    #pragma unroll
    for (int tt=0;tt<16;tt++) acc[tt]=0.f;
    #pragma unroll 5
    for (int q=0;q<25;q++){
      float4 wv = wr[q];
      #pragma unroll
      for (int tt=0;tt<16;tt++){
        float4 hv = *(const float4*)(s_hn + tt*100 + q*4);
        acc[tt] += wv.x*hv.x + wv.y*hv.y + wv.z*hv.z + wv.w*hv.w;
      }
    }
    float bb = outb[v];
    #pragma unroll
    for (int tt=0;tt<16;tt++){
      float lg = acc[tt] + bb;
      if (v == s_oid[tt]) ol[tt] = fmaxf(ol[tt], lg);
      if (lg <= rm[tt]) rs[tt] += __expf(lg - rm[tt]);
      else { rs[tt] = rs[tt]*__expf(rm[tt]-lg) + 1.0f; rm[tt]=lg; }
    }
  }
  int wv2=tid>>6, ln=tid&63;
  #pragma unroll
  for (int tt=0;tt<16;tt++){
    float m=rm[tt], sv=rs[tt], o=ol[tt];
    for (int d=1;d<64;d<<=1){
      float om=__shfl_xor(m,d,64), os=__shfl_xor(sv,d,64), oo=__shfl_xor(o,d,64);
      float M2=fmaxf(m,om);
      sv = sv*__expf(m-M2) + os*__expf(om-M2);
      m=M2; o=fmaxf(o,oo);
    }
    if (ln==0){ red[wv2][tt][0]=m; red[wv2][tt][1]=sv; red[wv2][tt][2]=o; }
  }
  __syncthreads();
  if (tid<16){
    float M=-1e30f;
    for (int q=0;q<4;q++) M=fmaxf(M,red[q][tid][0]);
    float S=0.f, O=-1e30f;
    for (int q=0;q<4;q++){ S += red[q][tid][1]*__expf(red[q][tid][0]-M); O=fmaxf(O,red[q][tid][2]); }
    float* pb = ws + OFF_PB + (((tile*2)+hf)*16 + tid)*4;
    pb[0]=M; pb[1]=S; pb[2]=O;
  }
}

// ---------------- kFinal: combine halves, sum, scale ----------------
__global__ void kFinal(const float* weight, float* ws, float* out){
  __shared__ float red[256];
  int tid=threadIdx.x;
  float acc=0.f;
  for (int t=tid;t<TLEN;t+=256){
    int tile=t>>4, tt=t&15;
    const float* p0 = ws + OFF_PB + ((tile*2+0)*16+tt)*4;
    const float* p1 = ws + OFF_PB + ((tile*2+1)*16+tt)*4;
    float M=fmaxf(p0[0],p1[0]);
    float S=p0[1]*__expf(p0[0]-M) + p1[1]*__expf(p1[0]-M);
    float O=fmaxf(p0[2],p1[2]);
    acc += (M + logf(S)) - O;
  }
  red[tid]=acc; __syncthreads();
  for (int d=128; d>0; d>>=1){
    if (tid<d) red[tid]+=red[tid+d];
    __syncthreads();
  }
  if (tid==0) out[0]=red[0]*weight[0];
}

// ---------------- launch ----------------
extern "C" void kernel_launch(void* const* d_in, const int* in_sizes, int n_in,
                              void* d_out, int out_size, void* d_ws, size_t ws_size,
                              hipStream_t stream) {
  const int*   src      = (const int*)  d_in[0];
  const int*   tag      = (const int*)  d_in[1];
  const int*   oid      = (const int*)  d_in[2];
  const float* weight   = (const float*)d_in[3];
  const float* emb_char = (const float*)d_in[4];
  const float* emb_tag  = (const float*)d_in[5];
  const float* fWih=(const float*)d_in[6],  *fWhh=(const float*)d_in[7],  *fb=(const float*)d_in[8];
  const float* bWih=(const float*)d_in[9],  *bWhh=(const float*)d_in[10], *bb=(const float*)d_in[11];
  const float* tWih=(const float*)d_in[12], *tWhh=(const float*)d_in[13], *tb=(const float*)d_in[14];
  const float* dWih=(const float*)d_in[15], *dWhh=(const float*)d_in[16], *db=(const float*)d_in[17];
  const float* aw1 =(const float*)d_in[18], *aw2=(const float*)d_in[19];
  const float* aw3 =(const float*)d_in[20], *av =(const float*)d_in[21];
  const float* taw1=(const float*)d_in[22], *taw2=(const float*)d_in[23], *tavv=(const float*)d_in[24];
  const float* outW=(const float*)d_in[25], *outb=(const float*)d_in[26];
  float* ws  = (float*)d_ws;
  float* out = (float*)d_out;

  kInit<<<8, 256, 0, stream>>>(ws);
  kPrep<<<2*NN+TTAG+TLEN, 512, 0, stream>>>(src,tag,oid,emb_char,emb_tag,
                                            fWih,fb,bWih,bb,tWih,tb,dWih,db,ws);
  kEnc<<<3,512,0,stream>>>(fWhh,bWhh,tWhh,taw1,dWih,ws);
  kMid<<<NN,128,0,stream>>>(aw1,ws);
  kDec<<<GW,512,0,stream>>>(dWhh,dWih,aw2,aw3,av,taw2,tavv,ws);
  kLoss<<<256,256,0,stream>>>(outW,outb,oid,ws);
  kFinal<<<1,256,0,stream>>>(weight,ws,out);
}